// Round 1
// baseline (3070.846 us; speedup 1.0000x reference)
//
#include <hip/hip_runtime.h>

#define DD 128   // embed dim
#define HH 256   // hidden dim
#define K1 256   // 2*DD
#define BM 64    // node tile

// ---------------- scatter: gather emb[src], atomic-add into nbr_sum[dst] ----
__global__ __launch_bounds__(256) void scatter_k(const float* __restrict__ emb,
        const int* __restrict__ src, const int* __restrict__ dst,
        float* nbr, float* __restrict__ cnt, int E) {
    int e = blockIdx.x * 8 + (threadIdx.x >> 5);
    if (e >= E) return;
    int lane = threadIdx.x & 31;
    int s = src[e];
    int d = dst[e];
    const float4 v = *reinterpret_cast<const float4*>(&emb[(size_t)s * DD + lane * 4]);
    float* o = &nbr[(size_t)d * DD + lane * 4];
    atomicAdd(o + 0, v.x);
    atomicAdd(o + 1, v.y);
    atomicAdd(o + 2, v.z);
    atomicAdd(o + 3, v.w);
    if (lane == 0) atomicAdd(&cnt[d], 1.0f);
}

// ---------------- fused mean + 2-layer MLP ---------------------------------
// per block: 64 nodes. LDS 64KB holds X[64][256] (concat) then H[64][256].
__global__ __launch_bounds__(256) void mlp_k(const float* __restrict__ emb,
        const float* nbr, const float* __restrict__ cnt,
        const float* __restrict__ W1, const float* __restrict__ b1,
        const float* __restrict__ W2, const float* __restrict__ b2,
        float* out, int N) {
    __shared__ float smem[BM * K1];  // 64 KB, X then H (aliased)
    const int t = threadIdx.x;
    const int n0 = blockIdx.x * BM;

    // ---- stage X = concat(emb, nbr_mean) ----
    // 64x256 floats = 4096 float4; 16 per thread; coalesced.
    #pragma unroll
    for (int it = 0; it < 16; ++it) {
        int idx = it * 256 + t;      // float4 index
        int r = idx >> 6;            // 64 float4 per row
        int c4 = idx & 63;
        int n = n0 + r;
        float4 v = make_float4(0.f, 0.f, 0.f, 0.f);
        if (n < N) {
            if (c4 < 32) {
                v = *reinterpret_cast<const float4*>(&emb[(size_t)n * DD + c4 * 4]);
            } else {
                float c = cnt[n];
                if (c > 0.f) {
                    v = *reinterpret_cast<const float4*>(&nbr[(size_t)n * DD + (c4 - 32) * 4]);
                    float inv = 1.f / c;
                    v.x *= inv; v.y *= inv; v.z *= inv; v.w *= inv;
                } else {
                    v = *reinterpret_cast<const float4*>(&emb[(size_t)n * DD + (c4 - 32) * 4]);
                }
            }
        }
        *reinterpret_cast<float4*>(&smem[idx * 4]) = v;
    }
    __syncthreads();

    const int tx = t & 31;
    const int ty = t >> 5;
    const int r0 = ty * 8;           // 8 row-groups of 8 rows

    // ---- GEMM1: H = relu(X @ W1 + b1), 8x8 per thread ----
    {
        const int c0 = tx * 8;       // 32 col-groups of 8 -> 256 cols
        float acc[8][8];
        const float4 bva = *reinterpret_cast<const float4*>(&b1[c0]);
        const float4 bvb = *reinterpret_cast<const float4*>(&b1[c0 + 4]);
        #pragma unroll
        for (int i = 0; i < 8; ++i) {
            acc[i][0] = bva.x; acc[i][1] = bva.y; acc[i][2] = bva.z; acc[i][3] = bva.w;
            acc[i][4] = bvb.x; acc[i][5] = bvb.y; acc[i][6] = bvb.z; acc[i][7] = bvb.w;
        }
        for (int k0 = 0; k0 < K1; k0 += 4) {
            float xs[8][4];
            #pragma unroll
            for (int i = 0; i < 8; ++i) {
                float4 xv = *reinterpret_cast<const float4*>(&smem[(r0 + i) * K1 + k0]);
                xs[i][0] = xv.x; xs[i][1] = xv.y; xs[i][2] = xv.z; xs[i][3] = xv.w;
            }
            #pragma unroll
            for (int kk = 0; kk < 4; ++kk) {
                const float4 wa = *reinterpret_cast<const float4*>(&W1[(size_t)(k0 + kk) * HH + c0]);
                const float4 wb = *reinterpret_cast<const float4*>(&W1[(size_t)(k0 + kk) * HH + c0 + 4]);
                #pragma unroll
                for (int i = 0; i < 8; ++i) {
                    float x = xs[i][kk];
                    acc[i][0] += x * wa.x; acc[i][1] += x * wa.y;
                    acc[i][2] += x * wa.z; acc[i][3] += x * wa.w;
                    acc[i][4] += x * wb.x; acc[i][5] += x * wb.y;
                    acc[i][6] += x * wb.z; acc[i][7] += x * wb.w;
                }
            }
        }
        __syncthreads();  // all X reads done; smem becomes H
        #pragma unroll
        for (int i = 0; i < 8; ++i) {
            float4 h0, h1;
            h0.x = fmaxf(acc[i][0], 0.f); h0.y = fmaxf(acc[i][1], 0.f);
            h0.z = fmaxf(acc[i][2], 0.f); h0.w = fmaxf(acc[i][3], 0.f);
            h1.x = fmaxf(acc[i][4], 0.f); h1.y = fmaxf(acc[i][5], 0.f);
            h1.z = fmaxf(acc[i][6], 0.f); h1.w = fmaxf(acc[i][7], 0.f);
            *reinterpret_cast<float4*>(&smem[(r0 + i) * HH + c0]) = h0;
            *reinterpret_cast<float4*>(&smem[(r0 + i) * HH + c0 + 4]) = h1;
        }
        __syncthreads();
    }

    // ---- GEMM2: out = H @ W2 + b2, 8x4 per thread ----
    {
        const int c0 = tx * 4;       // 32 col-groups of 4 -> 128 cols
        float acc[8][4];
        const float4 bv = *reinterpret_cast<const float4*>(&b2[c0]);
        #pragma unroll
        for (int i = 0; i < 8; ++i) {
            acc[i][0] = bv.x; acc[i][1] = bv.y; acc[i][2] = bv.z; acc[i][3] = bv.w;
        }
        for (int k0 = 0; k0 < HH; k0 += 4) {
            float hs[8][4];
            #pragma unroll
            for (int i = 0; i < 8; ++i) {
                float4 hv = *reinterpret_cast<const float4*>(&smem[(r0 + i) * HH + k0]);
                hs[i][0] = hv.x; hs[i][1] = hv.y; hs[i][2] = hv.z; hs[i][3] = hv.w;
            }
            #pragma unroll
            for (int kk = 0; kk < 4; ++kk) {
                const float4 w2 = *reinterpret_cast<const float4*>(&W2[(size_t)(k0 + kk) * DD + c0]);
                #pragma unroll
                for (int i = 0; i < 8; ++i) {
                    float h = hs[i][kk];
                    acc[i][0] += h * w2.x; acc[i][1] += h * w2.y;
                    acc[i][2] += h * w2.z; acc[i][3] += h * w2.w;
                }
            }
        }
        #pragma unroll
        for (int i = 0; i < 8; ++i) {
            int n = n0 + r0 + i;
            if (n < N) {
                float4 o;
                o.x = acc[i][0]; o.y = acc[i][1]; o.z = acc[i][2]; o.w = acc[i][3];
                *reinterpret_cast<float4*>(&out[(size_t)n * DD + c0]) = o;
            }
        }
    }
}

extern "C" void kernel_launch(void* const* d_in, const int* in_sizes, int n_in,
                              void* d_out, int out_size, void* d_ws, size_t ws_size,
                              hipStream_t stream) {
    const float* emb = (const float*)d_in[0];
    const int* esrc  = (const int*)d_in[1];
    const int* edst  = (const int*)d_in[2];
    const float* W1  = (const float*)d_in[3];
    const float* b1  = (const float*)d_in[4];
    const float* W2  = (const float*)d_in[5];
    const float* b2  = (const float*)d_in[6];
    float* out = (float*)d_out;

    const int N = in_sizes[0] / DD;
    const int E = in_sizes[1];

    float* nbr = out;              // accumulate nbr_sum directly in d_out (N*128 floats)
    float* cnt = (float*)d_ws;     // N floats of scratch

    hipMemsetAsync(nbr, 0, (size_t)N * DD * sizeof(float), stream);
    hipMemsetAsync(cnt, 0, (size_t)N * sizeof(float), stream);

    scatter_k<<<dim3((E + 7) / 8), dim3(256), 0, stream>>>(emb, esrc, edst, nbr, cnt, E);
    mlp_k<<<dim3((N + BM - 1) / BM), dim3(256), 0, stream>>>(emb, nbr, cnt, W1, b1, W2, b2, out, N);
}

// Round 2
// 594.590 us; speedup vs baseline: 5.1646x; 5.1646x over previous
//
#include <hip/hip_runtime.h>

#define DD 128   // embed dim
#define HH 256   // hidden dim
#define K1 256   // 2*DD
#define BM 64    // node tile

// ============================================================================
// Path A (fast): counting-sort edges by dst, then conflict-free segment reduce
// ============================================================================

// 1) histogram of dst
__global__ __launch_bounds__(256) void hist_k(const int* __restrict__ dst,
                                              int* __restrict__ cnt, int E) {
    for (int e = blockIdx.x * blockDim.x + threadIdx.x; e < E;
         e += gridDim.x * blockDim.x)
        atomicAdd(&cnt[dst[e]], 1);
}

// 2a) per-block (1024-elem) exclusive scan; block totals to part[]
__global__ __launch_bounds__(256) void scan1_k(const int* __restrict__ cnt,
                                               int* __restrict__ offs,
                                               int* __restrict__ part, int N) {
    __shared__ int sdata[256];
    const int b = blockIdx.x, t = threadIdx.x;
    const int base = b * 1024 + t * 4;
    int v[4], sum = 0;
    #pragma unroll
    for (int i = 0; i < 4; ++i) {
        int idx = base + i;
        v[i] = (idx < N) ? cnt[idx] : 0;
        sum += v[i];
    }
    sdata[t] = sum;
    __syncthreads();
    for (int off = 1; off < 256; off <<= 1) {
        int y = (t >= off) ? sdata[t - off] : 0;
        __syncthreads();
        sdata[t] += y;
        __syncthreads();
    }
    int excl = sdata[t] - sum;           // exclusive prefix of this thread
    if (t == 255) part[b] = sdata[255];  // block total
    int run = excl;
    #pragma unroll
    for (int i = 0; i < 4; ++i) {
        int idx = base + i;
        if (idx < N) offs[idx] = run;
        run += v[i];
    }
}

// 2b) scan the (<=128) block totals in one block
__global__ __launch_bounds__(128) void scan2_k(int* __restrict__ part, int nparts) {
    __shared__ int sdata[128];
    const int t = threadIdx.x;
    int v = (t < nparts) ? part[t] : 0;
    sdata[t] = v;
    __syncthreads();
    for (int off = 1; off < 128; off <<= 1) {
        int y = (t >= off) ? sdata[t - off] : 0;
        __syncthreads();
        sdata[t] += y;
        __syncthreads();
    }
    if (t < nparts) part[t] = sdata[t] - v;  // exclusive
}

// 2c) add scanned block totals back
__global__ __launch_bounds__(256) void scan3_k(int* __restrict__ offs,
                                               const int* __restrict__ part, int N) {
    for (int i = blockIdx.x * blockDim.x + threadIdx.x; i < N;
         i += gridDim.x * blockDim.x)
        offs[i] += part[i >> 10];
}

// 3) bucket: place src indices in dst-sorted order; offs becomes segment ENDs
__global__ __launch_bounds__(256) void bucket_k(const int* __restrict__ src,
                                                const int* __restrict__ dst,
                                                int* __restrict__ offs,
                                                int* __restrict__ ssrc, int E) {
    for (int e = blockIdx.x * blockDim.x + threadIdx.x; e < E;
         e += gridDim.x * blockDim.x) {
        int pos = atomicAdd(&offs[dst[e]], 1);
        ssrc[pos] = src[e];
    }
}

// 4) per-dst gather-reduce + mean (+ empty fallback). One wave per dst.
__global__ __launch_bounds__(256) void gather_k(const float* __restrict__ emb,
                                                const int* __restrict__ offs,
                                                const int* __restrict__ ssrc,
                                                float* __restrict__ nbr, int N) {
    const int wid = threadIdx.x >> 6;
    const int lane = threadIdx.x & 63;
    const int d = blockIdx.x * 4 + wid;
    if (d >= N) return;
    const int start = (d == 0) ? 0 : offs[d - 1];  // end[d-1] == start[d]
    const int end = offs[d];
    float2 acc = make_float2(0.f, 0.f);
    int e = start;
    for (; e + 4 <= end; e += 4) {
        int s0 = ssrc[e], s1 = ssrc[e + 1], s2 = ssrc[e + 2], s3 = ssrc[e + 3];
        float2 v0 = *reinterpret_cast<const float2*>(&emb[(size_t)s0 * DD + lane * 2]);
        float2 v1 = *reinterpret_cast<const float2*>(&emb[(size_t)s1 * DD + lane * 2]);
        float2 v2 = *reinterpret_cast<const float2*>(&emb[(size_t)s2 * DD + lane * 2]);
        float2 v3 = *reinterpret_cast<const float2*>(&emb[(size_t)s3 * DD + lane * 2]);
        acc.x += v0.x + v1.x + v2.x + v3.x;
        acc.y += v0.y + v1.y + v2.y + v3.y;
    }
    for (; e < end; ++e) {
        int s = ssrc[e];
        float2 v = *reinterpret_cast<const float2*>(&emb[(size_t)s * DD + lane * 2]);
        acc.x += v.x; acc.y += v.y;
    }
    if (end > start) {
        float inv = 1.f / (float)(end - start);
        acc.x *= inv; acc.y *= inv;
    } else {
        acc = *reinterpret_cast<const float2*>(&emb[(size_t)d * DD + lane * 2]);
    }
    *reinterpret_cast<float2*>(&nbr[(size_t)d * DD + lane * 2]) = acc;
}

// ============================================================================
// Path B (fallback): original atomic scatter (used only if ws too small)
// ============================================================================
__global__ __launch_bounds__(256) void scatter_k(const float* __restrict__ emb,
        const int* __restrict__ src, const int* __restrict__ dst,
        float* nbr, float* __restrict__ cnt, int E) {
    int e = blockIdx.x * 8 + (threadIdx.x >> 5);
    if (e >= E) return;
    int lane = threadIdx.x & 31;
    int s = src[e];
    int d = dst[e];
    const float4 v = *reinterpret_cast<const float4*>(&emb[(size_t)s * DD + lane * 4]);
    float* o = &nbr[(size_t)d * DD + lane * 4];
    atomicAdd(o + 0, v.x);
    atomicAdd(o + 1, v.y);
    atomicAdd(o + 2, v.z);
    atomicAdd(o + 3, v.w);
    if (lane == 0) atomicAdd(&cnt[d], 1.0f);
}

// ============================================================================
// fused mean (optional) + 2-layer MLP. cnt==nullptr -> nbr already holds mean.
// ============================================================================
__global__ __launch_bounds__(256) void mlp_k(const float* __restrict__ emb,
        const float* nbr, const float* cnt,
        const float* __restrict__ W1, const float* __restrict__ b1,
        const float* __restrict__ W2, const float* __restrict__ b2,
        float* out, int N) {
    __shared__ float smem[BM * K1];  // 64 KB, X then H (aliased)
    const int t = threadIdx.x;
    const int n0 = blockIdx.x * BM;

    // ---- stage X = concat(emb, nbr_mean) ----
    #pragma unroll
    for (int it = 0; it < 16; ++it) {
        int idx = it * 256 + t;      // float4 index
        int r = idx >> 6;
        int c4 = idx & 63;
        int n = n0 + r;
        float4 v = make_float4(0.f, 0.f, 0.f, 0.f);
        if (n < N) {
            if (c4 < 32) {
                v = *reinterpret_cast<const float4*>(&emb[(size_t)n * DD + c4 * 4]);
            } else if (cnt == nullptr) {
                v = *reinterpret_cast<const float4*>(&nbr[(size_t)n * DD + (c4 - 32) * 4]);
            } else {
                float c = cnt[n];
                if (c > 0.f) {
                    v = *reinterpret_cast<const float4*>(&nbr[(size_t)n * DD + (c4 - 32) * 4]);
                    float inv = 1.f / c;
                    v.x *= inv; v.y *= inv; v.z *= inv; v.w *= inv;
                } else {
                    v = *reinterpret_cast<const float4*>(&emb[(size_t)n * DD + (c4 - 32) * 4]);
                }
            }
        }
        *reinterpret_cast<float4*>(&smem[idx * 4]) = v;
    }
    __syncthreads();

    const int tx = t & 31;
    const int ty = t >> 5;
    const int r0 = ty * 8;

    // ---- GEMM1: H = relu(X @ W1 + b1), 8x8 per thread ----
    {
        const int c0 = tx * 8;
        float acc[8][8];
        const float4 bva = *reinterpret_cast<const float4*>(&b1[c0]);
        const float4 bvb = *reinterpret_cast<const float4*>(&b1[c0 + 4]);
        #pragma unroll
        for (int i = 0; i < 8; ++i) {
            acc[i][0] = bva.x; acc[i][1] = bva.y; acc[i][2] = bva.z; acc[i][3] = bva.w;
            acc[i][4] = bvb.x; acc[i][5] = bvb.y; acc[i][6] = bvb.z; acc[i][7] = bvb.w;
        }
        for (int k0 = 0; k0 < K1; k0 += 4) {
            float xs[8][4];
            #pragma unroll
            for (int i = 0; i < 8; ++i) {
                float4 xv = *reinterpret_cast<const float4*>(&smem[(r0 + i) * K1 + k0]);
                xs[i][0] = xv.x; xs[i][1] = xv.y; xs[i][2] = xv.z; xs[i][3] = xv.w;
            }
            #pragma unroll
            for (int kk = 0; kk < 4; ++kk) {
                const float4 wa = *reinterpret_cast<const float4*>(&W1[(size_t)(k0 + kk) * HH + c0]);
                const float4 wb = *reinterpret_cast<const float4*>(&W1[(size_t)(k0 + kk) * HH + c0 + 4]);
                #pragma unroll
                for (int i = 0; i < 8; ++i) {
                    float x = xs[i][kk];
                    acc[i][0] += x * wa.x; acc[i][1] += x * wa.y;
                    acc[i][2] += x * wa.z; acc[i][3] += x * wa.w;
                    acc[i][4] += x * wb.x; acc[i][5] += x * wb.y;
                    acc[i][6] += x * wb.z; acc[i][7] += x * wb.w;
                }
            }
        }
        __syncthreads();
        #pragma unroll
        for (int i = 0; i < 8; ++i) {
            float4 h0, h1;
            h0.x = fmaxf(acc[i][0], 0.f); h0.y = fmaxf(acc[i][1], 0.f);
            h0.z = fmaxf(acc[i][2], 0.f); h0.w = fmaxf(acc[i][3], 0.f);
            h1.x = fmaxf(acc[i][4], 0.f); h1.y = fmaxf(acc[i][5], 0.f);
            h1.z = fmaxf(acc[i][6], 0.f); h1.w = fmaxf(acc[i][7], 0.f);
            *reinterpret_cast<float4*>(&smem[(r0 + i) * HH + c0]) = h0;
            *reinterpret_cast<float4*>(&smem[(r0 + i) * HH + c0 + 4]) = h1;
        }
        __syncthreads();
    }

    // ---- GEMM2: out = H @ W2 + b2, 8x4 per thread ----
    {
        const int c0 = tx * 4;
        float acc[8][4];
        const float4 bv = *reinterpret_cast<const float4*>(&b2[c0]);
        #pragma unroll
        for (int i = 0; i < 8; ++i) {
            acc[i][0] = bv.x; acc[i][1] = bv.y; acc[i][2] = bv.z; acc[i][3] = bv.w;
        }
        for (int k0 = 0; k0 < HH; k0 += 4) {
            float hs[8][4];
            #pragma unroll
            for (int i = 0; i < 8; ++i) {
                float4 hv = *reinterpret_cast<const float4*>(&smem[(r0 + i) * HH + k0]);
                hs[i][0] = hv.x; hs[i][1] = hv.y; hs[i][2] = hv.z; hs[i][3] = hv.w;
            }
            #pragma unroll
            for (int kk = 0; kk < 4; ++kk) {
                const float4 w2 = *reinterpret_cast<const float4*>(&W2[(size_t)(k0 + kk) * DD + c0]);
                #pragma unroll
                for (int i = 0; i < 8; ++i) {
                    float h = hs[i][kk];
                    acc[i][0] += h * w2.x; acc[i][1] += h * w2.y;
                    acc[i][2] += h * w2.z; acc[i][3] += h * w2.w;
                }
            }
        }
        #pragma unroll
        for (int i = 0; i < 8; ++i) {
            int n = n0 + r0 + i;
            if (n < N) {
                float4 o;
                o.x = acc[i][0]; o.y = acc[i][1]; o.z = acc[i][2]; o.w = acc[i][3];
                *reinterpret_cast<float4*>(&out[(size_t)n * DD + c0]) = o;
            }
        }
    }
}

extern "C" void kernel_launch(void* const* d_in, const int* in_sizes, int n_in,
                              void* d_out, int out_size, void* d_ws, size_t ws_size,
                              hipStream_t stream) {
    const float* emb = (const float*)d_in[0];
    const int* esrc  = (const int*)d_in[1];
    const int* edst  = (const int*)d_in[2];
    const float* W1  = (const float*)d_in[3];
    const float* b1  = (const float*)d_in[4];
    const float* W2  = (const float*)d_in[5];
    const float* b2  = (const float*)d_in[6];
    float* out = (float*)d_out;

    const int N = in_sizes[0] / DD;
    const int E = in_sizes[1];

    const size_t need = ((size_t)2 * N + 128 + (size_t)E) * sizeof(int);
    const int nparts = (N + 1023) / 1024;

    if (ws_size >= need && nparts <= 128) {
        // -------- fast path: sort-by-dst + segmented reduce --------
        int* cnt  = (int*)d_ws;              // N
        int* offs = cnt + N;                 // N
        int* part = offs + N;                // 128
        int* ssrc = part + 128;              // E

        hipMemsetAsync(cnt, 0, (size_t)N * sizeof(int), stream);
        hist_k<<<dim3(1024), dim3(256), 0, stream>>>(edst, cnt, E);
        scan1_k<<<dim3(nparts), dim3(256), 0, stream>>>(cnt, offs, part, N);
        scan2_k<<<dim3(1), dim3(128), 0, stream>>>(part, nparts);
        scan3_k<<<dim3(512), dim3(256), 0, stream>>>(offs, part, N);
        bucket_k<<<dim3(2048), dim3(256), 0, stream>>>(esrc, edst, offs, ssrc, E);
        gather_k<<<dim3((N + 3) / 4), dim3(256), 0, stream>>>(emb, offs, ssrc, out, N);
        mlp_k<<<dim3((N + BM - 1) / BM), dim3(256), 0, stream>>>(
            emb, out, nullptr, W1, b1, W2, b2, out, N);
    } else {
        // -------- fallback: atomic scatter --------
        float* cnt = (float*)d_ws;  // N floats
        hipMemsetAsync(out, 0, (size_t)N * DD * sizeof(float), stream);
        hipMemsetAsync(cnt, 0, (size_t)N * sizeof(float), stream);
        scatter_k<<<dim3((E + 7) / 8), dim3(256), 0, stream>>>(emb, esrc, edst, out, cnt, E);
        mlp_k<<<dim3((N + BM - 1) / BM), dim3(256), 0, stream>>>(
            emb, out, cnt, W1, b1, W2, b2, out, N);
    }
}

// Round 3
// 396.360 us; speedup vs baseline: 7.7476x; 1.5001x over previous
//
#include <hip/hip_runtime.h>

#define DD 128   // embed dim
#define HH 256   // hidden dim
#define K1 256   // 2*DD
#define BM 64    // node tile

typedef __bf16 bf16;
typedef __attribute__((ext_vector_type(8))) __bf16 bf16x8;
typedef __attribute__((ext_vector_type(4))) float f32x4;

// ============================================================================
// graph phase: counting-sort edges by dst, then conflict-free segment reduce
// ============================================================================

__global__ __launch_bounds__(256) void hist_k(const int* __restrict__ dst,
                                              int* __restrict__ cnt, int E) {
    for (int e = blockIdx.x * blockDim.x + threadIdx.x; e < E;
         e += gridDim.x * blockDim.x)
        atomicAdd(&cnt[dst[e]], 1);
}

__global__ __launch_bounds__(256) void scan1_k(const int* __restrict__ cnt,
                                               int* __restrict__ offs,
                                               int* __restrict__ part, int N) {
    __shared__ int sdata[256];
    const int b = blockIdx.x, t = threadIdx.x;
    const int base = b * 1024 + t * 4;
    int v[4], sum = 0;
    #pragma unroll
    for (int i = 0; i < 4; ++i) {
        int idx = base + i;
        v[i] = (idx < N) ? cnt[idx] : 0;
        sum += v[i];
    }
    sdata[t] = sum;
    __syncthreads();
    for (int off = 1; off < 256; off <<= 1) {
        int y = (t >= off) ? sdata[t - off] : 0;
        __syncthreads();
        sdata[t] += y;
        __syncthreads();
    }
    int excl = sdata[t] - sum;
    if (t == 255) part[b] = sdata[255];
    int run = excl;
    #pragma unroll
    for (int i = 0; i < 4; ++i) {
        int idx = base + i;
        if (idx < N) offs[idx] = run;
        run += v[i];
    }
}

__global__ __launch_bounds__(128) void scan2_k(int* __restrict__ part, int nparts) {
    __shared__ int sdata[128];
    const int t = threadIdx.x;
    int v = (t < nparts) ? part[t] : 0;
    sdata[t] = v;
    __syncthreads();
    for (int off = 1; off < 128; off <<= 1) {
        int y = (t >= off) ? sdata[t - off] : 0;
        __syncthreads();
        sdata[t] += y;
        __syncthreads();
    }
    if (t < nparts) part[t] = sdata[t] - v;
}

__global__ __launch_bounds__(256) void scan3_k(int* __restrict__ offs,
                                               const int* __restrict__ part, int N) {
    for (int i = blockIdx.x * blockDim.x + threadIdx.x; i < N;
         i += gridDim.x * blockDim.x)
        offs[i] += part[i >> 10];
}

__global__ __launch_bounds__(256) void bucket_k(const int* __restrict__ src,
                                                const int* __restrict__ dst,
                                                int* __restrict__ offs,
                                                int* __restrict__ ssrc, int E) {
    for (int e = blockIdx.x * blockDim.x + threadIdx.x; e < E;
         e += gridDim.x * blockDim.x) {
        int pos = atomicAdd(&offs[dst[e]], 1);
        ssrc[pos] = src[e];
    }
}

// one wave per dst: sum emb[src] rows over segment, mean, empty fallback
__global__ __launch_bounds__(256) void gather_k(const float* __restrict__ emb,
                                                const int* __restrict__ offs,
                                                const int* __restrict__ ssrc,
                                                float* __restrict__ nbr, int N) {
    const int wid = threadIdx.x >> 6;
    const int lane = threadIdx.x & 63;
    const int d = blockIdx.x * 4 + wid;
    if (d >= N) return;
    const int start = (d == 0) ? 0 : offs[d - 1];
    const int end = offs[d];
    float2 acc = make_float2(0.f, 0.f);
    int e = start;
    for (; e + 4 <= end; e += 4) {
        int s0 = ssrc[e], s1 = ssrc[e + 1], s2 = ssrc[e + 2], s3 = ssrc[e + 3];
        float2 v0 = *reinterpret_cast<const float2*>(&emb[(size_t)s0 * DD + lane * 2]);
        float2 v1 = *reinterpret_cast<const float2*>(&emb[(size_t)s1 * DD + lane * 2]);
        float2 v2 = *reinterpret_cast<const float2*>(&emb[(size_t)s2 * DD + lane * 2]);
        float2 v3 = *reinterpret_cast<const float2*>(&emb[(size_t)s3 * DD + lane * 2]);
        acc.x += v0.x + v1.x + v2.x + v3.x;
        acc.y += v0.y + v1.y + v2.y + v3.y;
    }
    for (; e < end; ++e) {
        int s = ssrc[e];
        float2 v = *reinterpret_cast<const float2*>(&emb[(size_t)s * DD + lane * 2]);
        acc.x += v.x; acc.y += v.y;
    }
    if (end > start) {
        float inv = 1.f / (float)(end - start);
        acc.x *= inv; acc.y *= inv;
    } else {
        acc = *reinterpret_cast<const float2*>(&emb[(size_t)d * DD + lane * 2]);
    }
    *reinterpret_cast<float2*>(&nbr[(size_t)d * DD + lane * 2]) = acc;
}

// ============================================================================
// W pre-pack: fp32 [K x NC] -> bf16 hi/lo planes in B-fragment order for
// mfma_f32_16x16x32_bf16. Fragment (kt,nt): lane l holds
// W[kt*32 + (l>>4)*8 + r][nt*16 + (l&15)], r=0..7 -> 16B per lane, coalesced.
// ============================================================================
__global__ __launch_bounds__(64) void pack_k(const float* __restrict__ W, int NC,
                                             bf16* __restrict__ hi,
                                             bf16* __restrict__ lo) {
    const int ntiles = NC >> 4;
    const int kt = blockIdx.x / ntiles;
    const int nt = blockIdx.x % ntiles;
    const int l = threadIdx.x;
    const int k0 = kt * 32 + (l >> 4) * 8;
    const int n = nt * 16 + (l & 15);
    bf16x8 hv, lv;
    #pragma unroll
    for (int r = 0; r < 8; ++r) {
        float w = W[(size_t)(k0 + r) * NC + n];
        bf16 h = (bf16)w;
        hv[r] = h;
        lv[r] = (bf16)(w - (float)h);
    }
    size_t off = ((size_t)blockIdx.x * 64 + l) * 8;
    *reinterpret_cast<bf16x8*>(hi + off) = hv;
    *reinterpret_cast<bf16x8*>(lo + off) = lv;
}

// ============================================================================
// MFMA MLP: stage X=concat(emb,nbr_mean) as swizzled bf16 hi/lo LDS planes,
// GEMM1 (relu) -> H back to same LDS, GEMM2 -> out. Split bf16: 3 MFMAs/tile.
// ============================================================================
__global__ __launch_bounds__(256) void mlp_mfma_k(const float* __restrict__ emb,
        const float* nbr,
        const bf16* __restrict__ w1h, const bf16* __restrict__ w1l,
        const float* __restrict__ b1,
        const bf16* __restrict__ w2h, const bf16* __restrict__ w2l,
        const float* __restrict__ b2,
        float* out, int N) {
    __shared__ char smem[BM * K1 * 4];  // 64 KB: hi plane [64][256], lo plane
    const int t = threadIdx.x;
    const int n0 = blockIdx.x * BM;
    const int l = t & 63;
    const int w = t >> 6;

    // ---- stage X hi/lo (swizzled: byte_in_row ^= (row&7)<<4) ----
    #pragma unroll
    for (int i = 0; i < 8; ++i) {
        int chunk = i * 256 + t;
        int row = chunk >> 5;            // 32 chunks of 8 per row
        int c0 = (chunk & 31) * 8;
        int n = n0 + row;
        float v[8];
        if (n < N) {
            const float* srcp = (c0 < DD) ? &emb[(size_t)n * DD + c0]
                                          : &nbr[(size_t)n * DD + (c0 - DD)];
            float4 a = *reinterpret_cast<const float4*>(srcp);
            float4 b = *reinterpret_cast<const float4*>(srcp + 4);
            v[0]=a.x; v[1]=a.y; v[2]=a.z; v[3]=a.w;
            v[4]=b.x; v[5]=b.y; v[6]=b.z; v[7]=b.w;
        } else {
            #pragma unroll
            for (int j = 0; j < 8; ++j) v[j] = 0.f;
        }
        bf16x8 hv, lv;
        #pragma unroll
        for (int j = 0; j < 8; ++j) {
            bf16 h = (bf16)v[j];
            hv[j] = h;
            lv[j] = (bf16)(v[j] - (float)h);
        }
        int off = row * 512 + ((c0 * 2) ^ ((row & 7) << 4));
        *reinterpret_cast<bf16x8*>(smem + off) = hv;
        *reinterpret_cast<bf16x8*>(smem + 32768 + off) = lv;
    }
    __syncthreads();

    const int arow = l & 15;
    const int abyte = (l >> 4) * 16;

    // ---- GEMM1: wave w owns cols [w*64, w*64+64) of H ----
    f32x4 acc[4][4];
    #pragma unroll
    for (int ntl = 0; ntl < 4; ++ntl) {
        float bv = b1[w * 64 + ntl * 16 + (l & 15)];
        #pragma unroll
        for (int mt = 0; mt < 4; ++mt)
            acc[mt][ntl] = (f32x4){bv, bv, bv, bv};
    }
    for (int kt = 0; kt < 8; ++kt) {
        bf16x8 ah[4], al[4];
        #pragma unroll
        for (int mt = 0; mt < 4; ++mt) {
            int row = mt * 16 + arow;
            int off = row * 512 + ((kt * 64 + abyte) ^ ((row & 7) << 4));
            ah[mt] = *reinterpret_cast<const bf16x8*>(smem + off);
            al[mt] = *reinterpret_cast<const bf16x8*>(smem + 32768 + off);
        }
        #pragma unroll
        for (int ntl = 0; ntl < 4; ++ntl) {
            int nt = w * 4 + ntl;
            size_t boff = ((size_t)(kt * 16 + nt) * 64 + l) * 8;
            bf16x8 bh = *reinterpret_cast<const bf16x8*>(w1h + boff);
            bf16x8 bl = *reinterpret_cast<const bf16x8*>(w1l + boff);
            #pragma unroll
            for (int mt = 0; mt < 4; ++mt) {
                acc[mt][ntl] = __builtin_amdgcn_mfma_f32_16x16x32_bf16(ah[mt], bh, acc[mt][ntl], 0, 0, 0);
                acc[mt][ntl] = __builtin_amdgcn_mfma_f32_16x16x32_bf16(ah[mt], bl, acc[mt][ntl], 0, 0, 0);
                acc[mt][ntl] = __builtin_amdgcn_mfma_f32_16x16x32_bf16(al[mt], bh, acc[mt][ntl], 0, 0, 0);
            }
        }
    }
    __syncthreads();  // all X reads done; LDS becomes H

    // ---- relu + write H hi/lo (same swizzle) ----
    #pragma unroll
    for (int mt = 0; mt < 4; ++mt)
        #pragma unroll
        for (int ntl = 0; ntl < 4; ++ntl) {
            int col = w * 64 + ntl * 16 + (l & 15);
            #pragma unroll
            for (int r = 0; r < 4; ++r) {
                int row = mt * 16 + (l >> 4) * 4 + r;
                float hval = fmaxf(acc[mt][ntl][r], 0.f);
                bf16 h = (bf16)hval;
                bf16 lo = (bf16)(hval - (float)h);
                int off = row * 512 + ((col * 2) ^ ((row & 7) << 4));
                *reinterpret_cast<bf16*>(smem + off) = h;
                *reinterpret_cast<bf16*>(smem + 32768 + off) = lo;
            }
        }
    __syncthreads();

    // ---- GEMM2: wave w owns cols [w*32, w*32+32) of out ----
    f32x4 acc2[4][2];
    #pragma unroll
    for (int ntl = 0; ntl < 2; ++ntl) {
        float bv = b2[w * 32 + ntl * 16 + (l & 15)];
        #pragma unroll
        for (int mt = 0; mt < 4; ++mt)
            acc2[mt][ntl] = (f32x4){bv, bv, bv, bv};
    }
    for (int kt = 0; kt < 8; ++kt) {
        bf16x8 ah[4], al[4];
        #pragma unroll
        for (int mt = 0; mt < 4; ++mt) {
            int row = mt * 16 + arow;
            int off = row * 512 + ((kt * 64 + abyte) ^ ((row & 7) << 4));
            ah[mt] = *reinterpret_cast<const bf16x8*>(smem + off);
            al[mt] = *reinterpret_cast<const bf16x8*>(smem + 32768 + off);
        }
        #pragma unroll
        for (int ntl = 0; ntl < 2; ++ntl) {
            int nt = w * 2 + ntl;
            size_t boff = ((size_t)(kt * 8 + nt) * 64 + l) * 8;
            bf16x8 bh = *reinterpret_cast<const bf16x8*>(w2h + boff);
            bf16x8 bl = *reinterpret_cast<const bf16x8*>(w2l + boff);
            #pragma unroll
            for (int mt = 0; mt < 4; ++mt) {
                acc2[mt][ntl] = __builtin_amdgcn_mfma_f32_16x16x32_bf16(ah[mt], bh, acc2[mt][ntl], 0, 0, 0);
                acc2[mt][ntl] = __builtin_amdgcn_mfma_f32_16x16x32_bf16(ah[mt], bl, acc2[mt][ntl], 0, 0, 0);
                acc2[mt][ntl] = __builtin_amdgcn_mfma_f32_16x16x32_bf16(al[mt], bh, acc2[mt][ntl], 0, 0, 0);
            }
        }
    }
    #pragma unroll
    for (int mt = 0; mt < 4; ++mt)
        #pragma unroll
        for (int ntl = 0; ntl < 2; ++ntl) {
            int col = w * 32 + ntl * 16 + (l & 15);
            #pragma unroll
            for (int r = 0; r < 4; ++r) {
                int row = mt * 16 + (l >> 4) * 4 + r;
                int n = n0 + row;
                if (n < N) out[(size_t)n * DD + col] = acc2[mt][ntl][r];
            }
        }
}

// ============================================================================
// fallback path (small ws): atomic scatter + fp32 VALU MLP
// ============================================================================
__global__ __launch_bounds__(256) void scatter_k(const float* __restrict__ emb,
        const int* __restrict__ src, const int* __restrict__ dst,
        float* nbr, float* __restrict__ cnt, int E) {
    int e = blockIdx.x * 8 + (threadIdx.x >> 5);
    if (e >= E) return;
    int lane = threadIdx.x & 31;
    int s = src[e];
    int d = dst[e];
    const float4 v = *reinterpret_cast<const float4*>(&emb[(size_t)s * DD + lane * 4]);
    float* o = &nbr[(size_t)d * DD + lane * 4];
    atomicAdd(o + 0, v.x);
    atomicAdd(o + 1, v.y);
    atomicAdd(o + 2, v.z);
    atomicAdd(o + 3, v.w);
    if (lane == 0) atomicAdd(&cnt[d], 1.0f);
}

__global__ __launch_bounds__(256) void mlp_k(const float* __restrict__ emb,
        const float* nbr, const float* cnt,
        const float* __restrict__ W1, const float* __restrict__ b1,
        const float* __restrict__ W2, const float* __restrict__ b2,
        float* out, int N) {
    __shared__ float smem[BM * K1];
    const int t = threadIdx.x;
    const int n0 = blockIdx.x * BM;
    #pragma unroll
    for (int it = 0; it < 16; ++it) {
        int idx = it * 256 + t;
        int r = idx >> 6;
        int c4 = idx & 63;
        int n = n0 + r;
        float4 v = make_float4(0.f, 0.f, 0.f, 0.f);
        if (n < N) {
            if (c4 < 32) {
                v = *reinterpret_cast<const float4*>(&emb[(size_t)n * DD + c4 * 4]);
            } else {
                float c = cnt[n];
                if (c > 0.f) {
                    v = *reinterpret_cast<const float4*>(&nbr[(size_t)n * DD + (c4 - 32) * 4]);
                    float inv = 1.f / c;
                    v.x *= inv; v.y *= inv; v.z *= inv; v.w *= inv;
                } else {
                    v = *reinterpret_cast<const float4*>(&emb[(size_t)n * DD + (c4 - 32) * 4]);
                }
            }
        }
        *reinterpret_cast<float4*>(&smem[idx * 4]) = v;
    }
    __syncthreads();
    const int tx = t & 31;
    const int ty = t >> 5;
    const int r0 = ty * 8;
    {
        const int c0 = tx * 8;
        float acc[8][8];
        const float4 bva = *reinterpret_cast<const float4*>(&b1[c0]);
        const float4 bvb = *reinterpret_cast<const float4*>(&b1[c0 + 4]);
        #pragma unroll
        for (int i = 0; i < 8; ++i) {
            acc[i][0] = bva.x; acc[i][1] = bva.y; acc[i][2] = bva.z; acc[i][3] = bva.w;
            acc[i][4] = bvb.x; acc[i][5] = bvb.y; acc[i][6] = bvb.z; acc[i][7] = bvb.w;
        }
        for (int k0 = 0; k0 < K1; k0 += 4) {
            float xs[8][4];
            #pragma unroll
            for (int i = 0; i < 8; ++i) {
                float4 xv = *reinterpret_cast<const float4*>(&smem[(r0 + i) * K1 + k0]);
                xs[i][0] = xv.x; xs[i][1] = xv.y; xs[i][2] = xv.z; xs[i][3] = xv.w;
            }
            #pragma unroll
            for (int kk = 0; kk < 4; ++kk) {
                const float4 wa = *reinterpret_cast<const float4*>(&W1[(size_t)(k0 + kk) * HH + c0]);
                const float4 wb = *reinterpret_cast<const float4*>(&W1[(size_t)(k0 + kk) * HH + c0 + 4]);
                #pragma unroll
                for (int i = 0; i < 8; ++i) {
                    float x = xs[i][kk];
                    acc[i][0] += x * wa.x; acc[i][1] += x * wa.y;
                    acc[i][2] += x * wa.z; acc[i][3] += x * wa.w;
                    acc[i][4] += x * wb.x; acc[i][5] += x * wb.y;
                    acc[i][6] += x * wb.z; acc[i][7] += x * wb.w;
                }
            }
        }
        __syncthreads();
        #pragma unroll
        for (int i = 0; i < 8; ++i) {
            float4 h0, h1;
            h0.x = fmaxf(acc[i][0], 0.f); h0.y = fmaxf(acc[i][1], 0.f);
            h0.z = fmaxf(acc[i][2], 0.f); h0.w = fmaxf(acc[i][3], 0.f);
            h1.x = fmaxf(acc[i][4], 0.f); h1.y = fmaxf(acc[i][5], 0.f);
            h1.z = fmaxf(acc[i][6], 0.f); h1.w = fmaxf(acc[i][7], 0.f);
            *reinterpret_cast<float4*>(&smem[(r0 + i) * HH + c0]) = h0;
            *reinterpret_cast<float4*>(&smem[(r0 + i) * HH + c0 + 4]) = h1;
        }
        __syncthreads();
    }
    {
        const int c0 = tx * 4;
        float acc[8][4];
        const float4 bv = *reinterpret_cast<const float4*>(&b2[c0]);
        #pragma unroll
        for (int i = 0; i < 8; ++i) {
            acc[i][0] = bv.x; acc[i][1] = bv.y; acc[i][2] = bv.z; acc[i][3] = bv.w;
        }
        for (int k0 = 0; k0 < HH; k0 += 4) {
            float hs[8][4];
            #pragma unroll
            for (int i = 0; i < 8; ++i) {
                float4 hv = *reinterpret_cast<const float4*>(&smem[(r0 + i) * HH + k0]);
                hs[i][0] = hv.x; hs[i][1] = hv.y; hs[i][2] = hv.z; hs[i][3] = hv.w;
            }
            #pragma unroll
            for (int kk = 0; kk < 4; ++kk) {
                const float4 w2 = *reinterpret_cast<const float4*>(&W2[(size_t)(k0 + kk) * DD + c0]);
                #pragma unroll
                for (int i = 0; i < 8; ++i) {
                    float h = hs[i][kk];
                    acc[i][0] += h * w2.x; acc[i][1] += h * w2.y;
                    acc[i][2] += h * w2.z; acc[i][3] += h * w2.w;
                }
            }
        }
        #pragma unroll
        for (int i = 0; i < 8; ++i) {
            int n = n0 + r0 + i;
            if (n < N) {
                float4 o;
                o.x = acc[i][0]; o.y = acc[i][1]; o.z = acc[i][2]; o.w = acc[i][3];
                *reinterpret_cast<float4*>(&out[(size_t)n * DD + c0]) = o;
            }
        }
    }
}

extern "C" void kernel_launch(void* const* d_in, const int* in_sizes, int n_in,
                              void* d_out, int out_size, void* d_ws, size_t ws_size,
                              hipStream_t stream) {
    const float* emb = (const float*)d_in[0];
    const int* esrc  = (const int*)d_in[1];
    const int* edst  = (const int*)d_in[2];
    const float* W1  = (const float*)d_in[3];
    const float* b1  = (const float*)d_in[4];
    const float* W2  = (const float*)d_in[5];
    const float* b2  = (const float*)d_in[6];
    float* out = (float*)d_out;

    const int N = in_sizes[0] / DD;
    const int E = in_sizes[1];
    const int nparts = (N + 1023) / 1024;

    // ws layout: cnt[N] offs[N] part[128] ssrc[E] | align16 | W packs (384 KB)
    int* cnt  = (int*)d_ws;
    int* offs = cnt + N;
    int* part = offs + N;
    int* ssrc = part + 128;
    char* wp = (char*)(ssrc + E);
    wp = (char*)(((uintptr_t)wp + 15) & ~(uintptr_t)15);
    bf16* w1h = (bf16*)wp;            // 8kt*16nt*64*8 = 65536
    bf16* w1l = w1h + 65536;
    bf16* w2h = w1l + 65536;          // 8kt*8nt*64*8 = 32768
    bf16* w2l = w2h + 32768;
    const size_t need = (size_t)((char*)(w2l + 32768) - (char*)d_ws);

    if (ws_size >= need && nparts <= 128) {
        hipMemsetAsync(cnt, 0, (size_t)N * sizeof(int), stream);
        hist_k<<<dim3(1024), dim3(256), 0, stream>>>(edst, cnt, E);
        scan1_k<<<dim3(nparts), dim3(256), 0, stream>>>(cnt, offs, part, N);
        scan2_k<<<dim3(1), dim3(128), 0, stream>>>(part, nparts);
        scan3_k<<<dim3(512), dim3(256), 0, stream>>>(offs, part, N);
        bucket_k<<<dim3(2048), dim3(256), 0, stream>>>(esrc, edst, offs, ssrc, E);
        gather_k<<<dim3((N + 3) / 4), dim3(256), 0, stream>>>(emb, offs, ssrc, out, N);
        pack_k<<<dim3(128), dim3(64), 0, stream>>>(W1, HH, w1h, w1l);
        pack_k<<<dim3(64), dim3(64), 0, stream>>>(W2, DD, w2h, w2l);
        mlp_mfma_k<<<dim3((N + BM - 1) / BM), dim3(256), 0, stream>>>(
            emb, out, w1h, w1l, b1, w2h, w2l, b2, out, N);
    } else {
        float* fcnt = (float*)d_ws;
        hipMemsetAsync(out, 0, (size_t)N * DD * sizeof(float), stream);
        hipMemsetAsync(fcnt, 0, (size_t)N * sizeof(float), stream);
        scatter_k<<<dim3((E + 7) / 8), dim3(256), 0, stream>>>(emb, esrc, edst, out, fcnt, E);
        mlp_k<<<dim3((N + BM - 1) / BM), dim3(256), 0, stream>>>(
            emb, out, fcnt, W1, b1, W2, b2, out, N);
    }
}

// Round 4
// 362.054 us; speedup vs baseline: 8.4817x; 1.0948x over previous
//
#include <hip/hip_runtime.h>

#define DD 128   // embed dim
#define HH 256   // hidden dim
#define K1 256   // 2*DD
#define BM 64    // node tile
#define CH 2048  // edges per chunk in bucket scatter

typedef __bf16 bf16;
typedef __attribute__((ext_vector_type(8))) __bf16 bf16x8;
typedef __attribute__((ext_vector_type(4))) float f32x4;

// ============================================================================
// graph phase: counting-sort edges by dst, then conflict-free segment reduce
// ============================================================================

__global__ __launch_bounds__(256) void hist_k(const int* __restrict__ dst,
                                              int* __restrict__ cnt, int E) {
    for (int e = blockIdx.x * blockDim.x + threadIdx.x; e < E;
         e += gridDim.x * blockDim.x)
        atomicAdd(&cnt[dst[e]], 1);
}

__global__ __launch_bounds__(256) void scan1_k(const int* __restrict__ cnt,
                                               int* __restrict__ offs,
                                               int* __restrict__ part, int N) {
    __shared__ int sdata[256];
    const int b = blockIdx.x, t = threadIdx.x;
    const int base = b * 1024 + t * 4;
    int v[4], sum = 0;
    #pragma unroll
    for (int i = 0; i < 4; ++i) {
        int idx = base + i;
        v[i] = (idx < N) ? cnt[idx] : 0;
        sum += v[i];
    }
    sdata[t] = sum;
    __syncthreads();
    for (int off = 1; off < 256; off <<= 1) {
        int y = (t >= off) ? sdata[t - off] : 0;
        __syncthreads();
        sdata[t] += y;
        __syncthreads();
    }
    int excl = sdata[t] - sum;
    if (t == 255) part[b] = sdata[255];
    int run = excl;
    #pragma unroll
    for (int i = 0; i < 4; ++i) {
        int idx = base + i;
        if (idx < N) offs[idx] = run;
        run += v[i];
    }
}

__global__ __launch_bounds__(128) void scan2_k(int* __restrict__ part, int nparts) {
    __shared__ int sdata[128];
    const int t = threadIdx.x;
    int v = (t < nparts) ? part[t] : 0;
    sdata[t] = v;
    __syncthreads();
    for (int off = 1; off < 128; off <<= 1) {
        int y = (t >= off) ? sdata[t - off] : 0;
        __syncthreads();
        sdata[t] += y;
        __syncthreads();
    }
    if (t < nparts) part[t] = sdata[t] - v;
}

__global__ __launch_bounds__(256) void scan3_k(int* __restrict__ offs,
                                               const int* __restrict__ part, int N) {
    for (int i = blockIdx.x * blockDim.x + threadIdx.x; i < N;
         i += gridDim.x * blockDim.x)
        offs[i] += part[i >> 10];
}

// XCD/dst-range-partitioned bucket scatter: block (chunk, r=bid&7) reads its
// edge chunk and writes only edges whose dst falls in range r. With
// blockIdx%8 -> XCD round-robin, each 800KB ssrc subregion is written by one
// XCD's L2 only -> partial-line writebacks merge (kills the 16x write amp).
__global__ __launch_bounds__(256) void bucket_k(const int* __restrict__ src,
                                                const int* __restrict__ dst,
                                                int* __restrict__ offs,
                                                int* __restrict__ ssrc,
                                                int E, int N) {
    const int r = blockIdx.x & 7;
    const int chunk = blockIdx.x >> 3;
    const int lo = r * (N >> 3);
    const int hi = (r == 7) ? N : lo + (N >> 3);
    const int e0 = chunk * CH;
    const int e1 = min(E, e0 + CH);
    for (int e = e0 + threadIdx.x; e < e1; e += 256) {
        int d = dst[e];
        if (d >= lo && d < hi) {
            int pos = atomicAdd(&offs[d], 1);
            ssrc[pos] = src[e];
        }
    }
}

// one wave per dst: 2 edges/step (half-wave each, float4/lane), unroll x2,
// combine halves via shfl_xor(32).
__global__ __launch_bounds__(256) void gather_k(const float* __restrict__ emb,
                                                const int* __restrict__ offs,
                                                const int* __restrict__ ssrc,
                                                float* __restrict__ nbr, int N) {
    const int wid = threadIdx.x >> 6;
    const int lane = threadIdx.x & 63;
    const int d = blockIdx.x * 4 + wid;
    if (d >= N) return;
    const int sub = lane >> 5;       // which edge of the pair
    const int c = (lane & 31) * 4;   // float4 column
    const int start = (d == 0) ? 0 : offs[d - 1];
    const int end = offs[d];
    float4 acc = make_float4(0.f, 0.f, 0.f, 0.f);
    int e = start;
    for (; e + 4 <= end; e += 4) {
        int s0 = ssrc[e + sub];
        int s1 = ssrc[e + 2 + sub];
        float4 v0 = *reinterpret_cast<const float4*>(&emb[(size_t)s0 * DD + c]);
        float4 v1 = *reinterpret_cast<const float4*>(&emb[(size_t)s1 * DD + c]);
        acc.x += v0.x + v1.x; acc.y += v0.y + v1.y;
        acc.z += v0.z + v1.z; acc.w += v0.w + v1.w;
    }
    for (; e + 2 <= end; e += 2) {
        int s = ssrc[e + sub];
        float4 v = *reinterpret_cast<const float4*>(&emb[(size_t)s * DD + c]);
        acc.x += v.x; acc.y += v.y; acc.z += v.z; acc.w += v.w;
    }
    if (e < end && sub == 0) {
        int s = ssrc[e];
        float4 v = *reinterpret_cast<const float4*>(&emb[(size_t)s * DD + c]);
        acc.x += v.x; acc.y += v.y; acc.z += v.z; acc.w += v.w;
    }
    // combine the two half-wave partial sums
    acc.x += __shfl_xor(acc.x, 32);
    acc.y += __shfl_xor(acc.y, 32);
    acc.z += __shfl_xor(acc.z, 32);
    acc.w += __shfl_xor(acc.w, 32);
    if (sub == 0) {
        if (end > start) {
            float inv = 1.f / (float)(end - start);
            acc.x *= inv; acc.y *= inv; acc.z *= inv; acc.w *= inv;
        } else {
            acc = *reinterpret_cast<const float4*>(&emb[(size_t)d * DD + c]);
        }
        *reinterpret_cast<float4*>(&nbr[(size_t)d * DD + c]) = acc;
    }
}

// ============================================================================
// W pre-pack: fp32 [K x NC] -> bf16 (hi only) in B-fragment order for
// mfma_f32_16x16x32_bf16. Fragment (kt,nt): lane l holds
// W[kt*32 + (l>>4)*8 + r][nt*16 + (l&15)], r=0..7 -> 16B per lane, coalesced.
// ============================================================================
__global__ __launch_bounds__(64) void pack_k(const float* __restrict__ W, int NC,
                                             bf16* __restrict__ hi) {
    const int ntiles = NC >> 4;
    const int kt = blockIdx.x / ntiles;
    const int nt = blockIdx.x % ntiles;
    const int l = threadIdx.x;
    const int k0 = kt * 32 + (l >> 4) * 8;
    const int n = nt * 16 + (l & 15);
    bf16x8 hv;
    #pragma unroll
    for (int r = 0; r < 8; ++r)
        hv[r] = (bf16)W[(size_t)(k0 + r) * NC + n];
    *reinterpret_cast<bf16x8*>(hi + ((size_t)blockIdx.x * 64 + l) * 8) = hv;
}

// ============================================================================
// MFMA MLP: 2-term split precision (Xhi*Whi + Xlo*Whi = fp32-X x bf16-W).
// X staged as swizzled bf16 hi/lo LDS planes; H likewise for GEMM2.
// ============================================================================
__global__ __launch_bounds__(256) void mlp_mfma_k(const float* __restrict__ emb,
        const float* nbr,
        const bf16* __restrict__ w1h, const float* __restrict__ b1,
        const bf16* __restrict__ w2h, const float* __restrict__ b2,
        float* out, int N) {
    __shared__ char smem[BM * K1 * 4];  // 64 KB: hi plane [64][256], lo plane
    const int t = threadIdx.x;
    const int n0 = blockIdx.x * BM;
    const int l = t & 63;
    const int w = t >> 6;

    // ---- stage X hi/lo (swizzled: byte_in_row ^= (row&7)<<4) ----
    #pragma unroll
    for (int i = 0; i < 8; ++i) {
        int chunk = i * 256 + t;
        int row = chunk >> 5;            // 32 chunks of 8 per row
        int c0 = (chunk & 31) * 8;
        int n = n0 + row;
        float v[8];
        if (n < N) {
            const float* srcp = (c0 < DD) ? &emb[(size_t)n * DD + c0]
                                          : &nbr[(size_t)n * DD + (c0 - DD)];
            float4 a = *reinterpret_cast<const float4*>(srcp);
            float4 b = *reinterpret_cast<const float4*>(srcp + 4);
            v[0]=a.x; v[1]=a.y; v[2]=a.z; v[3]=a.w;
            v[4]=b.x; v[5]=b.y; v[6]=b.z; v[7]=b.w;
        } else {
            #pragma unroll
            for (int j = 0; j < 8; ++j) v[j] = 0.f;
        }
        bf16x8 hv, lv;
        #pragma unroll
        for (int j = 0; j < 8; ++j) {
            bf16 h = (bf16)v[j];
            hv[j] = h;
            lv[j] = (bf16)(v[j] - (float)h);
        }
        int off = row * 512 + ((c0 * 2) ^ ((row & 7) << 4));
        *reinterpret_cast<bf16x8*>(smem + off) = hv;
        *reinterpret_cast<bf16x8*>(smem + 32768 + off) = lv;
    }
    __syncthreads();

    const int arow = l & 15;
    const int abyte = (l >> 4) * 16;

    // ---- GEMM1: wave w owns cols [w*64, w*64+64) of H ----
    f32x4 acc[4][4];
    #pragma unroll
    for (int ntl = 0; ntl < 4; ++ntl) {
        float bv = b1[w * 64 + ntl * 16 + (l & 15)];
        #pragma unroll
        for (int mt = 0; mt < 4; ++mt)
            acc[mt][ntl] = (f32x4){bv, bv, bv, bv};
    }
    for (int kt = 0; kt < 8; ++kt) {
        bf16x8 ah[4], al[4];
        #pragma unroll
        for (int mt = 0; mt < 4; ++mt) {
            int row = mt * 16 + arow;
            int off = row * 512 + ((kt * 64 + abyte) ^ ((row & 7) << 4));
            ah[mt] = *reinterpret_cast<const bf16x8*>(smem + off);
            al[mt] = *reinterpret_cast<const bf16x8*>(smem + 32768 + off);
        }
        #pragma unroll
        for (int ntl = 0; ntl < 4; ++ntl) {
            int nt = w * 4 + ntl;
            size_t boff = ((size_t)(kt * 16 + nt) * 64 + l) * 8;
            bf16x8 bh = *reinterpret_cast<const bf16x8*>(w1h + boff);
            #pragma unroll
            for (int mt = 0; mt < 4; ++mt) {
                acc[mt][ntl] = __builtin_amdgcn_mfma_f32_16x16x32_bf16(ah[mt], bh, acc[mt][ntl], 0, 0, 0);
                acc[mt][ntl] = __builtin_amdgcn_mfma_f32_16x16x32_bf16(al[mt], bh, acc[mt][ntl], 0, 0, 0);
            }
        }
    }
    __syncthreads();  // all X reads done; LDS becomes H

    // ---- relu + write H hi/lo (same swizzle) ----
    #pragma unroll
    for (int mt = 0; mt < 4; ++mt)
        #pragma unroll
        for (int ntl = 0; ntl < 4; ++ntl) {
            int col = w * 64 + ntl * 16 + (l & 15);
            #pragma unroll
            for (int r = 0; r < 4; ++r) {
                int row = mt * 16 + (l >> 4) * 4 + r;
                float hval = fmaxf(acc[mt][ntl][r], 0.f);
                bf16 h = (bf16)hval;
                bf16 lo = (bf16)(hval - (float)h);
                int off = row * 512 + ((col * 2) ^ ((row & 7) << 4));
                *reinterpret_cast<bf16*>(smem + off) = h;
                *reinterpret_cast<bf16*>(smem + 32768 + off) = lo;
            }
        }
    __syncthreads();

    // ---- GEMM2: wave w owns cols [w*32, w*32+32) of out ----
    f32x4 acc2[4][2];
    #pragma unroll
    for (int ntl = 0; ntl < 2; ++ntl) {
        float bv = b2[w * 32 + ntl * 16 + (l & 15)];
        #pragma unroll
        for (int mt = 0; mt < 4; ++mt)
            acc2[mt][ntl] = (f32x4){bv, bv, bv, bv};
    }
    for (int kt = 0; kt < 8; ++kt) {
        bf16x8 ah[4], al[4];
        #pragma unroll
        for (int mt = 0; mt < 4; ++mt) {
            int row = mt * 16 + arow;
            int off = row * 512 + ((kt * 64 + abyte) ^ ((row & 7) << 4));
            ah[mt] = *reinterpret_cast<const bf16x8*>(smem + off);
            al[mt] = *reinterpret_cast<const bf16x8*>(smem + 32768 + off);
        }
        #pragma unroll
        for (int ntl = 0; ntl < 2; ++ntl) {
            int nt = w * 2 + ntl;
            size_t boff = ((size_t)(kt * 8 + nt) * 64 + l) * 8;
            bf16x8 bh = *reinterpret_cast<const bf16x8*>(w2h + boff);
            #pragma unroll
            for (int mt = 0; mt < 4; ++mt) {
                acc2[mt][ntl] = __builtin_amdgcn_mfma_f32_16x16x32_bf16(ah[mt], bh, acc2[mt][ntl], 0, 0, 0);
                acc2[mt][ntl] = __builtin_amdgcn_mfma_f32_16x16x32_bf16(al[mt], bh, acc2[mt][ntl], 0, 0, 0);
            }
        }
    }
    #pragma unroll
    for (int mt = 0; mt < 4; ++mt)
        #pragma unroll
        for (int ntl = 0; ntl < 2; ++ntl) {
            int col = w * 32 + ntl * 16 + (l & 15);
            #pragma unroll
            for (int r = 0; r < 4; ++r) {
                int row = mt * 16 + (l >> 4) * 4 + r;
                int n = n0 + row;
                if (n < N) out[(size_t)n * DD + col] = acc2[mt][ntl][r];
            }
        }
}

// ============================================================================
// fallback path (small ws): atomic scatter + fp32 VALU MLP
// ============================================================================
__global__ __launch_bounds__(256) void scatter_k(const float* __restrict__ emb,
        const int* __restrict__ src, const int* __restrict__ dst,
        float* nbr, float* __restrict__ cnt, int E) {
    int e = blockIdx.x * 8 + (threadIdx.x >> 5);
    if (e >= E) return;
    int lane = threadIdx.x & 31;
    int s = src[e];
    int d = dst[e];
    const float4 v = *reinterpret_cast<const float4*>(&emb[(size_t)s * DD + lane * 4]);
    float* o = &nbr[(size_t)d * DD + lane * 4];
    atomicAdd(o + 0, v.x);
    atomicAdd(o + 1, v.y);
    atomicAdd(o + 2, v.z);
    atomicAdd(o + 3, v.w);
    if (lane == 0) atomicAdd(&cnt[d], 1.0f);
}

__global__ __launch_bounds__(256) void mlp_k(const float* __restrict__ emb,
        const float* nbr, const float* cnt,
        const float* __restrict__ W1, const float* __restrict__ b1,
        const float* __restrict__ W2, const float* __restrict__ b2,
        float* out, int N) {
    __shared__ float smem[BM * K1];
    const int t = threadIdx.x;
    const int n0 = blockIdx.x * BM;
    #pragma unroll
    for (int it = 0; it < 16; ++it) {
        int idx = it * 256 + t;
        int r = idx >> 6;
        int c4 = idx & 63;
        int n = n0 + r;
        float4 v = make_float4(0.f, 0.f, 0.f, 0.f);
        if (n < N) {
            if (c4 < 32) {
                v = *reinterpret_cast<const float4*>(&emb[(size_t)n * DD + c4 * 4]);
            } else {
                float c = cnt[n];
                if (c > 0.f) {
                    v = *reinterpret_cast<const float4*>(&nbr[(size_t)n * DD + (c4 - 32) * 4]);
                    float inv = 1.f / c;
                    v.x *= inv; v.y *= inv; v.z *= inv; v.w *= inv;
                } else {
                    v = *reinterpret_cast<const float4*>(&emb[(size_t)n * DD + (c4 - 32) * 4]);
                }
            }
        }
        *reinterpret_cast<float4*>(&smem[idx * 4]) = v;
    }
    __syncthreads();
    const int tx = t & 31;
    const int ty = t >> 5;
    const int r0 = ty * 8;
    {
        const int c0 = tx * 8;
        float acc[8][8];
        const float4 bva = *reinterpret_cast<const float4*>(&b1[c0]);
        const float4 bvb = *reinterpret_cast<const float4*>(&b1[c0 + 4]);
        #pragma unroll
        for (int i = 0; i < 8; ++i) {
            acc[i][0] = bva.x; acc[i][1] = bva.y; acc[i][2] = bva.z; acc[i][3] = bva.w;
            acc[i][4] = bvb.x; acc[i][5] = bvb.y; acc[i][6] = bvb.z; acc[i][7] = bvb.w;
        }
        for (int k0 = 0; k0 < K1; k0 += 4) {
            float xs[8][4];
            #pragma unroll
            for (int i = 0; i < 8; ++i) {
                float4 xv = *reinterpret_cast<const float4*>(&smem[(r0 + i) * K1 + k0]);
                xs[i][0] = xv.x; xs[i][1] = xv.y; xs[i][2] = xv.z; xs[i][3] = xv.w;
            }
            #pragma unroll
            for (int kk = 0; kk < 4; ++kk) {
                const float4 wa = *reinterpret_cast<const float4*>(&W1[(size_t)(k0 + kk) * HH + c0]);
                const float4 wb = *reinterpret_cast<const float4*>(&W1[(size_t)(k0 + kk) * HH + c0 + 4]);
                #pragma unroll
                for (int i = 0; i < 8; ++i) {
                    float x = xs[i][kk];
                    acc[i][0] += x * wa.x; acc[i][1] += x * wa.y;
                    acc[i][2] += x * wa.z; acc[i][3] += x * wa.w;
                    acc[i][4] += x * wb.x; acc[i][5] += x * wb.y;
                    acc[i][6] += x * wb.z; acc[i][7] += x * wb.w;
                }
            }
        }
        __syncthreads();
        #pragma unroll
        for (int i = 0; i < 8; ++i) {
            float4 h0, h1;
            h0.x = fmaxf(acc[i][0], 0.f); h0.y = fmaxf(acc[i][1], 0.f);
            h0.z = fmaxf(acc[i][2], 0.f); h0.w = fmaxf(acc[i][3], 0.f);
            h1.x = fmaxf(acc[i][4], 0.f); h1.y = fmaxf(acc[i][5], 0.f);
            h1.z = fmaxf(acc[i][6], 0.f); h1.w = fmaxf(acc[i][7], 0.f);
            *reinterpret_cast<float4*>(&smem[(r0 + i) * HH + c0]) = h0;
            *reinterpret_cast<float4*>(&smem[(r0 + i) * HH + c0 + 4]) = h1;
        }
        __syncthreads();
    }
    {
        const int c0 = tx * 4;
        float acc[8][4];
        const float4 bv = *reinterpret_cast<const float4*>(&b2[c0]);
        #pragma unroll
        for (int i = 0; i < 8; ++i) {
            acc[i][0] = bv.x; acc[i][1] = bv.y; acc[i][2] = bv.z; acc[i][3] = bv.w;
        }
        for (int k0 = 0; k0 < HH; k0 += 4) {
            float hs[8][4];
            #pragma unroll
            for (int i = 0; i < 8; ++i) {
                float4 hv = *reinterpret_cast<const float4*>(&smem[(r0 + i) * HH + k0]);
                hs[i][0] = hv.x; hs[i][1] = hv.y; hs[i][2] = hv.z; hs[i][3] = hv.w;
            }
            #pragma unroll
            for (int kk = 0; kk < 4; ++kk) {
                const float4 w2 = *reinterpret_cast<const float4*>(&W2[(size_t)(k0 + kk) * DD + c0]);
                #pragma unroll
                for (int i = 0; i < 8; ++i) {
                    float h = hs[i][kk];
                    acc[i][0] += h * w2.x; acc[i][1] += h * w2.y;
                    acc[i][2] += h * w2.z; acc[i][3] += h * w2.w;
                }
            }
        }
        #pragma unroll
        for (int i = 0; i < 8; ++i) {
            int n = n0 + r0 + i;
            if (n < N) {
                float4 o;
                o.x = acc[i][0]; o.y = acc[i][1]; o.z = acc[i][2]; o.w = acc[i][3];
                *reinterpret_cast<float4*>(&out[(size_t)n * DD + c0]) = o;
            }
        }
    }
}

extern "C" void kernel_launch(void* const* d_in, const int* in_sizes, int n_in,
                              void* d_out, int out_size, void* d_ws, size_t ws_size,
                              hipStream_t stream) {
    const float* emb = (const float*)d_in[0];
    const int* esrc  = (const int*)d_in[1];
    const int* edst  = (const int*)d_in[2];
    const float* W1  = (const float*)d_in[3];
    const float* b1  = (const float*)d_in[4];
    const float* W2  = (const float*)d_in[5];
    const float* b2  = (const float*)d_in[6];
    float* out = (float*)d_out;

    const int N = in_sizes[0] / DD;
    const int E = in_sizes[1];
    const int nparts = (N + 1023) / 1024;

    // ws layout: cnt[N] offs[N] part[128] ssrc[E] | align16 | W packs (192 KB)
    int* cnt  = (int*)d_ws;
    int* offs = cnt + N;
    int* part = offs + N;
    int* ssrc = part + 128;
    char* wp = (char*)(ssrc + E);
    wp = (char*)(((uintptr_t)wp + 15) & ~(uintptr_t)15);
    bf16* w1h = (bf16*)wp;            // 8kt*16nt*64*8 = 65536 elems
    bf16* w2h = w1h + 65536;          // 8kt*8nt*64*8 = 32768 elems
    const size_t need = (size_t)((char*)(w2h + 32768) - (char*)d_ws);

    if (ws_size >= need && nparts <= 128) {
        hipMemsetAsync(cnt, 0, (size_t)N * sizeof(int), stream);
        hist_k<<<dim3(1024), dim3(256), 0, stream>>>(edst, cnt, E);
        scan1_k<<<dim3(nparts), dim3(256), 0, stream>>>(cnt, offs, part, N);
        scan2_k<<<dim3(1), dim3(128), 0, stream>>>(part, nparts);
        scan3_k<<<dim3(512), dim3(256), 0, stream>>>(offs, part, N);
        pack_k<<<dim3(128), dim3(64), 0, stream>>>(W1, HH, w1h);
        pack_k<<<dim3(64), dim3(64), 0, stream>>>(W2, DD, w2h);
        const int nchunks = (E + CH - 1) / CH;
        bucket_k<<<dim3(nchunks * 8), dim3(256), 0, stream>>>(esrc, edst, offs, ssrc, E, N);
        gather_k<<<dim3((N + 3) / 4), dim3(256), 0, stream>>>(emb, offs, ssrc, out, N);
        mlp_mfma_k<<<dim3((N + BM - 1) / BM), dim3(256), 0, stream>>>(
            emb, out, w1h, b1, w2h, b2, out, N);
    } else {
        float* fcnt = (float*)d_ws;
        hipMemsetAsync(out, 0, (size_t)N * DD * sizeof(float), stream);
        hipMemsetAsync(fcnt, 0, (size_t)N * sizeof(float), stream);
        scatter_k<<<dim3((E + 7) / 8), dim3(256), 0, stream>>>(emb, esrc, edst, out, fcnt, E);
        mlp_k<<<dim3((N + BM - 1) / BM), dim3(256), 0, stream>>>(
            emb, out, fcnt, W1, b1, W2, b2, out, N);
    }
}

// Round 5
// 323.543 us; speedup vs baseline: 9.4913x; 1.1190x over previous
//
#include <hip/hip_runtime.h>

#define DD 128   // embed dim
#define HH 256   // hidden dim
#define K1 256   // 2*DD
#define BM 64    // node tile
#define CH 2048  // edges per chunk in bucket scatter

typedef __bf16 bf16;
typedef __attribute__((ext_vector_type(8))) __bf16 bf16x8;
typedef __attribute__((ext_vector_type(4))) float f32x4;

// ============================================================================
// graph phase: counting-sort edges by dst, then conflict-free segment reduce
// ============================================================================

__global__ __launch_bounds__(256) void hist_k(const int* __restrict__ dst,
                                              int* __restrict__ cnt, int E) {
    for (int e = blockIdx.x * blockDim.x + threadIdx.x; e < E;
         e += gridDim.x * blockDim.x)
        atomicAdd(&cnt[dst[e]], 1);
}

__global__ __launch_bounds__(256) void scan1_k(const int* __restrict__ cnt,
                                               int* __restrict__ offs,
                                               int* __restrict__ part, int N) {
    __shared__ int sdata[256];
    const int b = blockIdx.x, t = threadIdx.x;
    const int base = b * 1024 + t * 4;
    int v[4], sum = 0;
    #pragma unroll
    for (int i = 0; i < 4; ++i) {
        int idx = base + i;
        v[i] = (idx < N) ? cnt[idx] : 0;
        sum += v[i];
    }
    sdata[t] = sum;
    __syncthreads();
    for (int off = 1; off < 256; off <<= 1) {
        int y = (t >= off) ? sdata[t - off] : 0;
        __syncthreads();
        sdata[t] += y;
        __syncthreads();
    }
    int excl = sdata[t] - sum;
    if (t == 255) part[b] = sdata[255];
    int run = excl;
    #pragma unroll
    for (int i = 0; i < 4; ++i) {
        int idx = base + i;
        if (idx < N) offs[idx] = run;
        run += v[i];
    }
}

__global__ __launch_bounds__(128) void scan2_k(int* __restrict__ part, int nparts) {
    __shared__ int sdata[128];
    const int t = threadIdx.x;
    int v = (t < nparts) ? part[t] : 0;
    sdata[t] = v;
    __syncthreads();
    for (int off = 1; off < 128; off <<= 1) {
        int y = (t >= off) ? sdata[t - off] : 0;
        __syncthreads();
        sdata[t] += y;
        __syncthreads();
    }
    if (t < nparts) part[t] = sdata[t] - v;
}

__global__ __launch_bounds__(256) void scan3_k(int* __restrict__ offs,
                                               const int* __restrict__ part, int N) {
    for (int i = blockIdx.x * blockDim.x + threadIdx.x; i < N;
         i += gridDim.x * blockDim.x)
        offs[i] += part[i >> 10];
}

// XCD/dst-range-partitioned bucket scatter (kills partial-line write amp)
__global__ __launch_bounds__(256) void bucket_k(const int* __restrict__ src,
                                                const int* __restrict__ dst,
                                                int* __restrict__ offs,
                                                int* __restrict__ ssrc,
                                                int E, int N) {
    const int r = blockIdx.x & 7;
    const int chunk = blockIdx.x >> 3;
    const int lo = r * (N >> 3);
    const int hi = (r == 7) ? N : lo + (N >> 3);
    const int e0 = chunk * CH;
    const int e1 = min(E, e0 + CH);
    for (int e = e0 + threadIdx.x; e < e1; e += 256) {
        int d = dst[e];
        if (d >= lo && d < hi) {
            int pos = atomicAdd(&offs[d], 1);
            ssrc[pos] = src[e];
        }
    }
}

// emb fp32 -> bf16 copy (for the gather's random reads)
__global__ __launch_bounds__(256) void cvt_k(const float* __restrict__ emb,
                                             bf16* __restrict__ embh, size_t n8) {
    for (size_t i = blockIdx.x * blockDim.x + threadIdx.x; i < n8;
         i += (size_t)gridDim.x * blockDim.x) {
        float4 a = *reinterpret_cast<const float4*>(&emb[i * 8]);
        float4 b = *reinterpret_cast<const float4*>(&emb[i * 8 + 4]);
        bf16x8 v;
        v[0]=(bf16)a.x; v[1]=(bf16)a.y; v[2]=(bf16)a.z; v[3]=(bf16)a.w;
        v[4]=(bf16)b.x; v[5]=(bf16)b.y; v[6]=(bf16)b.z; v[7]=(bf16)b.w;
        *reinterpret_cast<bf16x8*>(&embh[i * 8]) = v;
    }
}

// one wave per dst, bf16 rows: 4 edges/step (16 lanes x 16B each), unroll x2
// -> 8 row-loads in flight; 2-level shfl_xor combine; fp32 accumulate.
__global__ __launch_bounds__(256) void gather_bf16_k(const bf16* __restrict__ embh,
                                                     const float* __restrict__ emb,
                                                     const int* __restrict__ offs,
                                                     const int* __restrict__ ssrc,
                                                     float* __restrict__ nbr, int N) {
    const int wid = threadIdx.x >> 6;
    const int lane = threadIdx.x & 63;
    const int d = blockIdx.x * 4 + wid;
    if (d >= N) return;
    const int sub = lane >> 4;       // which of 4 edges
    const int c8 = (lane & 15) * 8;  // bf16 column base
    const int start = (d == 0) ? 0 : offs[d - 1];
    const int end = offs[d];
    float acc[8];
    #pragma unroll
    for (int j = 0; j < 8; ++j) acc[j] = 0.f;
    int e = start;
    for (; e + 8 <= end; e += 8) {
        int s0 = ssrc[e + sub];
        int s1 = ssrc[e + 4 + sub];
        bf16x8 v0 = *reinterpret_cast<const bf16x8*>(&embh[(size_t)s0 * DD + c8]);
        bf16x8 v1 = *reinterpret_cast<const bf16x8*>(&embh[(size_t)s1 * DD + c8]);
        #pragma unroll
        for (int j = 0; j < 8; ++j) acc[j] += (float)v0[j] + (float)v1[j];
    }
    for (; e + 4 <= end; e += 4) {
        int s = ssrc[e + sub];
        bf16x8 v = *reinterpret_cast<const bf16x8*>(&embh[(size_t)s * DD + c8]);
        #pragma unroll
        for (int j = 0; j < 8; ++j) acc[j] += (float)v[j];
    }
    const int rem = end - e;
    if (sub < rem) {
        int s = ssrc[e + sub];
        bf16x8 v = *reinterpret_cast<const bf16x8*>(&embh[(size_t)s * DD + c8]);
        #pragma unroll
        for (int j = 0; j < 8; ++j) acc[j] += (float)v[j];
    }
    #pragma unroll
    for (int j = 0; j < 8; ++j) {
        acc[j] += __shfl_xor(acc[j], 16);
        acc[j] += __shfl_xor(acc[j], 32);
    }
    if (sub == 0) {
        float4 o0, o1;
        if (end > start) {
            float inv = 1.f / (float)(end - start);
            o0 = make_float4(acc[0]*inv, acc[1]*inv, acc[2]*inv, acc[3]*inv);
            o1 = make_float4(acc[4]*inv, acc[5]*inv, acc[6]*inv, acc[7]*inv);
        } else {
            o0 = *reinterpret_cast<const float4*>(&emb[(size_t)d * DD + c8]);
            o1 = *reinterpret_cast<const float4*>(&emb[(size_t)d * DD + c8 + 4]);
        }
        *reinterpret_cast<float4*>(&nbr[(size_t)d * DD + c8]) = o0;
        *reinterpret_cast<float4*>(&nbr[(size_t)d * DD + c8 + 4]) = o1;
    }
}

// fp32-row gather (used when ws can't fit the bf16 emb copy)
__global__ __launch_bounds__(256) void gather_k(const float* __restrict__ emb,
                                                const int* __restrict__ offs,
                                                const int* __restrict__ ssrc,
                                                float* __restrict__ nbr, int N) {
    const int wid = threadIdx.x >> 6;
    const int lane = threadIdx.x & 63;
    const int d = blockIdx.x * 4 + wid;
    if (d >= N) return;
    const int sub = lane >> 5;
    const int c = (lane & 31) * 4;
    const int start = (d == 0) ? 0 : offs[d - 1];
    const int end = offs[d];
    float4 acc = make_float4(0.f, 0.f, 0.f, 0.f);
    int e = start;
    for (; e + 4 <= end; e += 4) {
        int s0 = ssrc[e + sub];
        int s1 = ssrc[e + 2 + sub];
        float4 v0 = *reinterpret_cast<const float4*>(&emb[(size_t)s0 * DD + c]);
        float4 v1 = *reinterpret_cast<const float4*>(&emb[(size_t)s1 * DD + c]);
        acc.x += v0.x + v1.x; acc.y += v0.y + v1.y;
        acc.z += v0.z + v1.z; acc.w += v0.w + v1.w;
    }
    for (; e + 2 <= end; e += 2) {
        int s = ssrc[e + sub];
        float4 v = *reinterpret_cast<const float4*>(&emb[(size_t)s * DD + c]);
        acc.x += v.x; acc.y += v.y; acc.z += v.z; acc.w += v.w;
    }
    if (e < end && sub == 0) {
        int s = ssrc[e];
        float4 v = *reinterpret_cast<const float4*>(&emb[(size_t)s * DD + c]);
        acc.x += v.x; acc.y += v.y; acc.z += v.z; acc.w += v.w;
    }
    acc.x += __shfl_xor(acc.x, 32);
    acc.y += __shfl_xor(acc.y, 32);
    acc.z += __shfl_xor(acc.z, 32);
    acc.w += __shfl_xor(acc.w, 32);
    if (sub == 0) {
        if (end > start) {
            float inv = 1.f / (float)(end - start);
            acc.x *= inv; acc.y *= inv; acc.z *= inv; acc.w *= inv;
        } else {
            acc = *reinterpret_cast<const float4*>(&emb[(size_t)d * DD + c]);
        }
        *reinterpret_cast<float4*>(&nbr[(size_t)d * DD + c]) = acc;
    }
}

// ============================================================================
// W pre-pack: fp32 [K x NC] -> bf16 in B-fragment order for 16x16x32 MFMA.
// ============================================================================
__global__ __launch_bounds__(64) void pack_k(const float* __restrict__ W, int NC,
                                             bf16* __restrict__ hi) {
    const int ntiles = NC >> 4;
    const int kt = blockIdx.x / ntiles;
    const int nt = blockIdx.x % ntiles;
    const int l = threadIdx.x;
    const int k0 = kt * 32 + (l >> 4) * 8;
    const int n = nt * 16 + (l & 15);
    bf16x8 hv;
    #pragma unroll
    for (int r = 0; r < 8; ++r)
        hv[r] = (bf16)W[(size_t)(k0 + r) * NC + n];
    *reinterpret_cast<bf16x8*>(hi + ((size_t)blockIdx.x * 64 + l) * 8) = hv;
}

// ============================================================================
// MFMA MLP: 2-term split precision (Xhi*Whi + Xlo*Whi).
// ============================================================================
__global__ __launch_bounds__(256) void mlp_mfma_k(const float* __restrict__ emb,
        const float* nbr,
        const bf16* __restrict__ w1h, const float* __restrict__ b1,
        const bf16* __restrict__ w2h, const float* __restrict__ b2,
        float* out, int N) {
    __shared__ char smem[BM * K1 * 4];  // 64 KB: hi plane [64][256], lo plane
    const int t = threadIdx.x;
    const int n0 = blockIdx.x * BM;
    const int l = t & 63;
    const int w = t >> 6;

    #pragma unroll
    for (int i = 0; i < 8; ++i) {
        int chunk = i * 256 + t;
        int row = chunk >> 5;
        int c0 = (chunk & 31) * 8;
        int n = n0 + row;
        float v[8];
        if (n < N) {
            const float* srcp = (c0 < DD) ? &emb[(size_t)n * DD + c0]
                                          : &nbr[(size_t)n * DD + (c0 - DD)];
            float4 a = *reinterpret_cast<const float4*>(srcp);
            float4 b = *reinterpret_cast<const float4*>(srcp + 4);
            v[0]=a.x; v[1]=a.y; v[2]=a.z; v[3]=a.w;
            v[4]=b.x; v[5]=b.y; v[6]=b.z; v[7]=b.w;
        } else {
            #pragma unroll
            for (int j = 0; j < 8; ++j) v[j] = 0.f;
        }
        bf16x8 hv, lv;
        #pragma unroll
        for (int j = 0; j < 8; ++j) {
            bf16 h = (bf16)v[j];
            hv[j] = h;
            lv[j] = (bf16)(v[j] - (float)h);
        }
        int off = row * 512 + ((c0 * 2) ^ ((row & 7) << 4));
        *reinterpret_cast<bf16x8*>(smem + off) = hv;
        *reinterpret_cast<bf16x8*>(smem + 32768 + off) = lv;
    }
    __syncthreads();

    const int arow = l & 15;
    const int abyte = (l >> 4) * 16;

    f32x4 acc[4][4];
    #pragma unroll
    for (int ntl = 0; ntl < 4; ++ntl) {
        float bv = b1[w * 64 + ntl * 16 + (l & 15)];
        #pragma unroll
        for (int mt = 0; mt < 4; ++mt)
            acc[mt][ntl] = (f32x4){bv, bv, bv, bv};
    }
    for (int kt = 0; kt < 8; ++kt) {
        bf16x8 ah[4], al[4];
        #pragma unroll
        for (int mt = 0; mt < 4; ++mt) {
            int row = mt * 16 + arow;
            int off = row * 512 + ((kt * 64 + abyte) ^ ((row & 7) << 4));
            ah[mt] = *reinterpret_cast<const bf16x8*>(smem + off);
            al[mt] = *reinterpret_cast<const bf16x8*>(smem + 32768 + off);
        }
        #pragma unroll
        for (int ntl = 0; ntl < 4; ++ntl) {
            int nt = w * 4 + ntl;
            size_t boff = ((size_t)(kt * 16 + nt) * 64 + l) * 8;
            bf16x8 bh = *reinterpret_cast<const bf16x8*>(w1h + boff);
            #pragma unroll
            for (int mt = 0; mt < 4; ++mt) {
                acc[mt][ntl] = __builtin_amdgcn_mfma_f32_16x16x32_bf16(ah[mt], bh, acc[mt][ntl], 0, 0, 0);
                acc[mt][ntl] = __builtin_amdgcn_mfma_f32_16x16x32_bf16(al[mt], bh, acc[mt][ntl], 0, 0, 0);
            }
        }
    }
    __syncthreads();

    #pragma unroll
    for (int mt = 0; mt < 4; ++mt)
        #pragma unroll
        for (int ntl = 0; ntl < 4; ++ntl) {
            int col = w * 64 + ntl * 16 + (l & 15);
            #pragma unroll
            for (int r = 0; r < 4; ++r) {
                int row = mt * 16 + (l >> 4) * 4 + r;
                float hval = fmaxf(acc[mt][ntl][r], 0.f);
                bf16 h = (bf16)hval;
                bf16 lo = (bf16)(hval - (float)h);
                int off = row * 512 + ((col * 2) ^ ((row & 7) << 4));
                *reinterpret_cast<bf16*>(smem + off) = h;
                *reinterpret_cast<bf16*>(smem + 32768 + off) = lo;
            }
        }
    __syncthreads();

    f32x4 acc2[4][2];
    #pragma unroll
    for (int ntl = 0; ntl < 2; ++ntl) {
        float bv = b2[w * 32 + ntl * 16 + (l & 15)];
        #pragma unroll
        for (int mt = 0; mt < 4; ++mt)
            acc2[mt][ntl] = (f32x4){bv, bv, bv, bv};
    }
    for (int kt = 0; kt < 8; ++kt) {
        bf16x8 ah[4], al[4];
        #pragma unroll
        for (int mt = 0; mt < 4; ++mt) {
            int row = mt * 16 + arow;
            int off = row * 512 + ((kt * 64 + abyte) ^ ((row & 7) << 4));
            ah[mt] = *reinterpret_cast<const bf16x8*>(smem + off);
            al[mt] = *reinterpret_cast<const bf16x8*>(smem + 32768 + off);
        }
        #pragma unroll
        for (int ntl = 0; ntl < 2; ++ntl) {
            int nt = w * 2 + ntl;
            size_t boff = ((size_t)(kt * 8 + nt) * 64 + l) * 8;
            bf16x8 bh = *reinterpret_cast<const bf16x8*>(w2h + boff);
            #pragma unroll
            for (int mt = 0; mt < 4; ++mt) {
                acc2[mt][ntl] = __builtin_amdgcn_mfma_f32_16x16x32_bf16(ah[mt], bh, acc2[mt][ntl], 0, 0, 0);
                acc2[mt][ntl] = __builtin_amdgcn_mfma_f32_16x16x32_bf16(al[mt], bh, acc2[mt][ntl], 0, 0, 0);
            }
        }
    }
    #pragma unroll
    for (int mt = 0; mt < 4; ++mt)
        #pragma unroll
        for (int ntl = 0; ntl < 2; ++ntl) {
            int col = w * 32 + ntl * 16 + (l & 15);
            #pragma unroll
            for (int r = 0; r < 4; ++r) {
                int row = mt * 16 + (l >> 4) * 4 + r;
                int n = n0 + row;
                if (n < N) out[(size_t)n * DD + col] = acc2[mt][ntl][r];
            }
        }
}

// ============================================================================
// fallback path (tiny ws): atomic scatter + fp32 VALU MLP
// ============================================================================
__global__ __launch_bounds__(256) void scatter_k(const float* __restrict__ emb,
        const int* __restrict__ src, const int* __restrict__ dst,
        float* nbr, float* __restrict__ cnt, int E) {
    int e = blockIdx.x * 8 + (threadIdx.x >> 5);
    if (e >= E) return;
    int lane = threadIdx.x & 31;
    int s = src[e];
    int d = dst[e];
    const float4 v = *reinterpret_cast<const float4*>(&emb[(size_t)s * DD + lane * 4]);
    float* o = &nbr[(size_t)d * DD + lane * 4];
    atomicAdd(o + 0, v.x);
    atomicAdd(o + 1, v.y);
    atomicAdd(o + 2, v.z);
    atomicAdd(o + 3, v.w);
    if (lane == 0) atomicAdd(&cnt[d], 1.0f);
}

__global__ __launch_bounds__(256) void mlp_k(const float* __restrict__ emb,
        const float* nbr, const float* cnt,
        const float* __restrict__ W1, const float* __restrict__ b1,
        const float* __restrict__ W2, const float* __restrict__ b2,
        float* out, int N) {
    __shared__ float smem[BM * K1];
    const int t = threadIdx.x;
    const int n0 = blockIdx.x * BM;
    #pragma unroll
    for (int it = 0; it < 16; ++it) {
        int idx = it * 256 + t;
        int r = idx >> 6;
        int c4 = idx & 63;
        int n = n0 + r;
        float4 v = make_float4(0.f, 0.f, 0.f, 0.f);
        if (n < N) {
            if (c4 < 32) {
                v = *reinterpret_cast<const float4*>(&emb[(size_t)n * DD + c4 * 4]);
            } else {
                float c = cnt[n];
                if (c > 0.f) {
                    v = *reinterpret_cast<const float4*>(&nbr[(size_t)n * DD + (c4 - 32) * 4]);
                    float inv = 1.f / c;
                    v.x *= inv; v.y *= inv; v.z *= inv; v.w *= inv;
                } else {
                    v = *reinterpret_cast<const float4*>(&emb[(size_t)n * DD + (c4 - 32) * 4]);
                }
            }
        }
        *reinterpret_cast<float4*>(&smem[idx * 4]) = v;
    }
    __syncthreads();
    const int tx = t & 31;
    const int ty = t >> 5;
    const int r0 = ty * 8;
    {
        const int c0 = tx * 8;
        float acc[8][8];
        const float4 bva = *reinterpret_cast<const float4*>(&b1[c0]);
        const float4 bvb = *reinterpret_cast<const float4*>(&b1[c0 + 4]);
        #pragma unroll
        for (int i = 0; i < 8; ++i) {
            acc[i][0] = bva.x; acc[i][1] = bva.y; acc[i][2] = bva.z; acc[i][3] = bva.w;
            acc[i][4] = bvb.x; acc[i][5] = bvb.y; acc[i][6] = bvb.z; acc[i][7] = bvb.w;
        }
        for (int k0 = 0; k0 < K1; k0 += 4) {
            float xs[8][4];
            #pragma unroll
            for (int i = 0; i < 8; ++i) {
                float4 xv = *reinterpret_cast<const float4*>(&smem[(r0 + i) * K1 + k0]);
                xs[i][0] = xv.x; xs[i][1] = xv.y; xs[i][2] = xv.z; xs[i][3] = xv.w;
            }
            #pragma unroll
            for (int kk = 0; kk < 4; ++kk) {
                const float4 wa = *reinterpret_cast<const float4*>(&W1[(size_t)(k0 + kk) * HH + c0]);
                const float4 wb = *reinterpret_cast<const float4*>(&W1[(size_t)(k0 + kk) * HH + c0 + 4]);
                #pragma unroll
                for (int i = 0; i < 8; ++i) {
                    float x = xs[i][kk];
                    acc[i][0] += x * wa.x; acc[i][1] += x * wa.y;
                    acc[i][2] += x * wa.z; acc[i][3] += x * wa.w;
                    acc[i][4] += x * wb.x; acc[i][5] += x * wb.y;
                    acc[i][6] += x * wb.z; acc[i][7] += x * wb.w;
                }
            }
        }
        __syncthreads();
        #pragma unroll
        for (int i = 0; i < 8; ++i) {
            float4 h0, h1;
            h0.x = fmaxf(acc[i][0], 0.f); h0.y = fmaxf(acc[i][1], 0.f);
            h0.z = fmaxf(acc[i][2], 0.f); h0.w = fmaxf(acc[i][3], 0.f);
            h1.x = fmaxf(acc[i][4], 0.f); h1.y = fmaxf(acc[i][5], 0.f);
            h1.z = fmaxf(acc[i][6], 0.f); h1.w = fmaxf(acc[i][7], 0.f);
            *reinterpret_cast<float4*>(&smem[(r0 + i) * HH + c0]) = h0;
            *reinterpret_cast<float4*>(&smem[(r0 + i) * HH + c0 + 4]) = h1;
        }
        __syncthreads();
    }
    {
        const int c0 = tx * 4;
        float acc[8][4];
        const float4 bv = *reinterpret_cast<const float4*>(&b2[c0]);
        #pragma unroll
        for (int i = 0; i < 8; ++i) {
            acc[i][0] = bv.x; acc[i][1] = bv.y; acc[i][2] = bv.z; acc[i][3] = bv.w;
        }
        for (int k0 = 0; k0 < HH; k0 += 4) {
            float hs[8][4];
            #pragma unroll
            for (int i = 0; i < 8; ++i) {
                float4 hv = *reinterpret_cast<const float4*>(&smem[(r0 + i) * HH + k0]);
                hs[i][0] = hv.x; hs[i][1] = hv.y; hs[i][2] = hv.z; hs[i][3] = hv.w;
            }
            #pragma unroll
            for (int kk = 0; kk < 4; ++kk) {
                const float4 w2 = *reinterpret_cast<const float4*>(&W2[(size_t)(k0 + kk) * DD + c0]);
                #pragma unroll
                for (int i = 0; i < 8; ++i) {
                    float h = hs[i][kk];
                    acc[i][0] += h * w2.x; acc[i][1] += h * w2.y;
                    acc[i][2] += h * w2.z; acc[i][3] += h * w2.w;
                }
            }
        }
        #pragma unroll
        for (int i = 0; i < 8; ++i) {
            int n = n0 + r0 + i;
            if (n < N) {
                float4 o;
                o.x = acc[i][0]; o.y = acc[i][1]; o.z = acc[i][2]; o.w = acc[i][3];
                *reinterpret_cast<float4*>(&out[(size_t)n * DD + c0]) = o;
            }
        }
    }
}

extern "C" void kernel_launch(void* const* d_in, const int* in_sizes, int n_in,
                              void* d_out, int out_size, void* d_ws, size_t ws_size,
                              hipStream_t stream) {
    const float* emb = (const float*)d_in[0];
    const int* esrc  = (const int*)d_in[1];
    const int* edst  = (const int*)d_in[2];
    const float* W1  = (const float*)d_in[3];
    const float* b1  = (const float*)d_in[4];
    const float* W2  = (const float*)d_in[5];
    const float* b2  = (const float*)d_in[6];
    float* out = (float*)d_out;

    const int N = in_sizes[0] / DD;
    const int E = in_sizes[1];
    const int nparts = (N + 1023) / 1024;

    // ws layout: cnt[N] offs[N] part[128] ssrc[E] | W packs | embh (bf16 N*DD)
    int* cnt  = (int*)d_ws;
    int* offs = cnt + N;
    int* part = offs + N;
    int* ssrc = part + 128;
    char* wp = (char*)(ssrc + E);
    wp = (char*)(((uintptr_t)wp + 15) & ~(uintptr_t)15);
    bf16* w1h = (bf16*)wp;            // 65536 elems
    bf16* w2h = w1h + 65536;          // 32768 elems
    bf16* embh = w2h + 32768;         // N*DD elems
    const size_t need_base = (size_t)((char*)(w2h + 32768) - (char*)d_ws);
    const size_t need_bf16 = (size_t)((char*)(embh + (size_t)N * DD) - (char*)d_ws);

    if (ws_size >= need_base && nparts <= 128) {
        hipMemsetAsync(cnt, 0, (size_t)N * sizeof(int), stream);
        hist_k<<<dim3(1024), dim3(256), 0, stream>>>(edst, cnt, E);
        scan1_k<<<dim3(nparts), dim3(256), 0, stream>>>(cnt, offs, part, N);
        scan2_k<<<dim3(1), dim3(128), 0, stream>>>(part, nparts);
        scan3_k<<<dim3(512), dim3(256), 0, stream>>>(offs, part, N);
        pack_k<<<dim3(128), dim3(64), 0, stream>>>(W1, HH, w1h);
        pack_k<<<dim3(64), dim3(64), 0, stream>>>(W2, DD, w2h);
        if (ws_size >= need_bf16)
            cvt_k<<<dim3(2048), dim3(256), 0, stream>>>(emb, embh, (size_t)N * DD / 8);
        const int nchunks = (E + CH - 1) / CH;
        bucket_k<<<dim3(nchunks * 8), dim3(256), 0, stream>>>(esrc, edst, offs, ssrc, E, N);
        if (ws_size >= need_bf16)
            gather_bf16_k<<<dim3((N + 3) / 4), dim3(256), 0, stream>>>(embh, emb, offs, ssrc, out, N);
        else
            gather_k<<<dim3((N + 3) / 4), dim3(256), 0, stream>>>(emb, offs, ssrc, out, N);
        mlp_mfma_k<<<dim3((N + BM - 1) / BM), dim3(256), 0, stream>>>(
            emb, out, w1h, b1, w2h, b2, out, N);
    } else {
        float* fcnt = (float*)d_ws;
        hipMemsetAsync(out, 0, (size_t)N * DD * sizeof(float), stream);
        hipMemsetAsync(fcnt, 0, (size_t)N * sizeof(float), stream);
        scatter_k<<<dim3((E + 7) / 8), dim3(256), 0, stream>>>(emb, esrc, edst, out, fcnt, E);
        mlp_k<<<dim3((N + BM - 1) / BM), dim3(256), 0, stream>>>(
            emb, out, fcnt, W1, b1, W2, b2, out, N);
    }
}

// Round 6
// 277.446 us; speedup vs baseline: 11.0683x; 1.1661x over previous
//
#include <hip/hip_runtime.h>

#define DD 128   // embed dim
#define HH 256   // hidden dim
#define K1 256   // 2*DD
#define BM 64    // node tile
#define CH 2048  // edges per chunk in bucket scatter

typedef __bf16 bf16;
typedef __attribute__((ext_vector_type(8))) __bf16 bf16x8;
typedef __attribute__((ext_vector_type(4))) float f32x4;

// ============================================================================
// graph phase: counting-sort edges by dst, then conflict-free segment reduce
// ============================================================================

__global__ __launch_bounds__(256) void hist_k(const int* __restrict__ dst,
                                              int* __restrict__ cnt, int E) {
    for (int e = blockIdx.x * blockDim.x + threadIdx.x; e < E;
         e += gridDim.x * blockDim.x)
        atomicAdd(&cnt[dst[e]], 1);
}

__global__ __launch_bounds__(256) void scan1_k(const int* __restrict__ cnt,
                                               int* __restrict__ offs,
                                               int* __restrict__ part, int N) {
    __shared__ int sdata[256];
    const int b = blockIdx.x, t = threadIdx.x;
    const int base = b * 1024 + t * 4;
    int v[4], sum = 0;
    #pragma unroll
    for (int i = 0; i < 4; ++i) {
        int idx = base + i;
        v[i] = (idx < N) ? cnt[idx] : 0;
        sum += v[i];
    }
    sdata[t] = sum;
    __syncthreads();
    for (int off = 1; off < 256; off <<= 1) {
        int y = (t >= off) ? sdata[t - off] : 0;
        __syncthreads();
        sdata[t] += y;
        __syncthreads();
    }
    int excl = sdata[t] - sum;
    if (t == 255) part[b] = sdata[255];
    int run = excl;
    #pragma unroll
    for (int i = 0; i < 4; ++i) {
        int idx = base + i;
        if (idx < N) offs[idx] = run;
        run += v[i];
    }
}

__global__ __launch_bounds__(128) void scan2_k(int* __restrict__ part, int nparts) {
    __shared__ int sdata[128];
    const int t = threadIdx.x;
    int v = (t < nparts) ? part[t] : 0;
    sdata[t] = v;
    __syncthreads();
    for (int off = 1; off < 128; off <<= 1) {
        int y = (t >= off) ? sdata[t - off] : 0;
        __syncthreads();
        sdata[t] += y;
        __syncthreads();
    }
    if (t < nparts) part[t] = sdata[t] - v;
}

__global__ __launch_bounds__(256) void scan3_k(int* __restrict__ offs,
                                               const int* __restrict__ part, int N) {
    for (int i = blockIdx.x * blockDim.x + threadIdx.x; i < N;
         i += gridDim.x * blockDim.x)
        offs[i] += part[i >> 10];
}

// XCD/dst-range-partitioned bucket scatter (kills partial-line write amp)
__global__ __launch_bounds__(256) void bucket_k(const int* __restrict__ src,
                                                const int* __restrict__ dst,
                                                int* __restrict__ offs,
                                                int* __restrict__ ssrc,
                                                int E, int N) {
    const int r = blockIdx.x & 7;
    const int chunk = blockIdx.x >> 3;
    const int lo = r * (N >> 3);
    const int hi = (r == 7) ? N : lo + (N >> 3);
    const int e0 = chunk * CH;
    const int e1 = min(E, e0 + CH);
    for (int e = e0 + threadIdx.x; e < e1; e += 256) {
        int d = dst[e];
        if (d >= lo && d < hi) {
            int pos = atomicAdd(&offs[d], 1);
            ssrc[pos] = src[e];
        }
    }
}

// emb fp32 -> bf16 copy
__global__ __launch_bounds__(256) void cvt_k(const float* __restrict__ emb,
                                             bf16* __restrict__ embh, size_t n8) {
    for (size_t i = blockIdx.x * blockDim.x + threadIdx.x; i < n8;
         i += (size_t)gridDim.x * blockDim.x) {
        float4 a = *reinterpret_cast<const float4*>(&emb[i * 8]);
        float4 b = *reinterpret_cast<const float4*>(&emb[i * 8 + 4]);
        bf16x8 v;
        v[0]=(bf16)a.x; v[1]=(bf16)a.y; v[2]=(bf16)a.z; v[3]=(bf16)a.w;
        v[4]=(bf16)b.x; v[5]=(bf16)b.y; v[6]=(bf16)b.z; v[7]=(bf16)b.w;
        *reinterpret_cast<bf16x8*>(&embh[i * 8]) = v;
    }
}

// one wave per dst, bf16 rows: 4 edges/step, unroll x2 -> 8 row-loads in
// flight; 2-level shfl_xor combine; fp32 accumulate; bf16 output row.
__global__ __launch_bounds__(256) void gather_bf16_k(const bf16* __restrict__ embh,
                                                     const int* __restrict__ offs,
                                                     const int* __restrict__ ssrc,
                                                     bf16* __restrict__ nbrh, int N) {
    const int wid = threadIdx.x >> 6;
    const int lane = threadIdx.x & 63;
    const int d = blockIdx.x * 4 + wid;
    if (d >= N) return;
    const int sub = lane >> 4;       // which of 4 edges
    const int c8 = (lane & 15) * 8;  // bf16 column base
    const int start = (d == 0) ? 0 : offs[d - 1];
    const int end = offs[d];
    float acc[8];
    #pragma unroll
    for (int j = 0; j < 8; ++j) acc[j] = 0.f;
    int e = start;
    for (; e + 8 <= end; e += 8) {
        int s0 = ssrc[e + sub];
        int s1 = ssrc[e + 4 + sub];
        bf16x8 v0 = *reinterpret_cast<const bf16x8*>(&embh[(size_t)s0 * DD + c8]);
        bf16x8 v1 = *reinterpret_cast<const bf16x8*>(&embh[(size_t)s1 * DD + c8]);
        #pragma unroll
        for (int j = 0; j < 8; ++j) acc[j] += (float)v0[j] + (float)v1[j];
    }
    for (; e + 4 <= end; e += 4) {
        int s = ssrc[e + sub];
        bf16x8 v = *reinterpret_cast<const bf16x8*>(&embh[(size_t)s * DD + c8]);
        #pragma unroll
        for (int j = 0; j < 8; ++j) acc[j] += (float)v[j];
    }
    const int rem = end - e;
    if (sub < rem) {
        int s = ssrc[e + sub];
        bf16x8 v = *reinterpret_cast<const bf16x8*>(&embh[(size_t)s * DD + c8]);
        #pragma unroll
        for (int j = 0; j < 8; ++j) acc[j] += (float)v[j];
    }
    #pragma unroll
    for (int j = 0; j < 8; ++j) {
        acc[j] += __shfl_xor(acc[j], 16);
        acc[j] += __shfl_xor(acc[j], 32);
    }
    if (sub == 0) {
        bf16x8 o;
        if (end > start) {
            float inv = 1.f / (float)(end - start);
            #pragma unroll
            for (int j = 0; j < 8; ++j) o[j] = (bf16)(acc[j] * inv);
        } else {
            o = *reinterpret_cast<const bf16x8*>(&embh[(size_t)d * DD + c8]);
        }
        *reinterpret_cast<bf16x8*>(&nbrh[(size_t)d * DD + c8]) = o;
    }
}

// fp32-row gather (used when ws can't fit the bf16 buffers); writes fp32 nbr
__global__ __launch_bounds__(256) void gather_k(const float* __restrict__ emb,
                                                const int* __restrict__ offs,
                                                const int* __restrict__ ssrc,
                                                float* __restrict__ nbr, int N) {
    const int wid = threadIdx.x >> 6;
    const int lane = threadIdx.x & 63;
    const int d = blockIdx.x * 4 + wid;
    if (d >= N) return;
    const int sub = lane >> 5;
    const int c = (lane & 31) * 4;
    const int start = (d == 0) ? 0 : offs[d - 1];
    const int end = offs[d];
    float4 acc = make_float4(0.f, 0.f, 0.f, 0.f);
    int e = start;
    for (; e + 4 <= end; e += 4) {
        int s0 = ssrc[e + sub];
        int s1 = ssrc[e + 2 + sub];
        float4 v0 = *reinterpret_cast<const float4*>(&emb[(size_t)s0 * DD + c]);
        float4 v1 = *reinterpret_cast<const float4*>(&emb[(size_t)s1 * DD + c]);
        acc.x += v0.x + v1.x; acc.y += v0.y + v1.y;
        acc.z += v0.z + v1.z; acc.w += v0.w + v1.w;
    }
    for (; e + 2 <= end; e += 2) {
        int s = ssrc[e + sub];
        float4 v = *reinterpret_cast<const float4*>(&emb[(size_t)s * DD + c]);
        acc.x += v.x; acc.y += v.y; acc.z += v.z; acc.w += v.w;
    }
    if (e < end && sub == 0) {
        int s = ssrc[e];
        float4 v = *reinterpret_cast<const float4*>(&emb[(size_t)s * DD + c]);
        acc.x += v.x; acc.y += v.y; acc.z += v.z; acc.w += v.w;
    }
    acc.x += __shfl_xor(acc.x, 32);
    acc.y += __shfl_xor(acc.y, 32);
    acc.z += __shfl_xor(acc.z, 32);
    acc.w += __shfl_xor(acc.w, 32);
    if (sub == 0) {
        if (end > start) {
            float inv = 1.f / (float)(end - start);
            acc.x *= inv; acc.y *= inv; acc.z *= inv; acc.w *= inv;
        } else {
            acc = *reinterpret_cast<const float4*>(&emb[(size_t)d * DD + c]);
        }
        *reinterpret_cast<float4*>(&nbr[(size_t)d * DD + c]) = acc;
    }
}

// ============================================================================
// W pre-pack: fp32 [K x NC] -> bf16 in B-fragment order for 16x16x32 MFMA.
// ============================================================================
__global__ __launch_bounds__(64) void pack_k(const float* __restrict__ W, int NC,
                                             bf16* __restrict__ hi) {
    const int ntiles = NC >> 4;
    const int kt = blockIdx.x / ntiles;
    const int nt = blockIdx.x % ntiles;
    const int l = threadIdx.x;
    const int k0 = kt * 32 + (l >> 4) * 8;
    const int n = nt * 16 + (l & 15);
    bf16x8 hv;
    #pragma unroll
    for (int r = 0; r < 8; ++r)
        hv[r] = (bf16)W[(size_t)(k0 + r) * NC + n];
    *reinterpret_cast<bf16x8*>(hi + ((size_t)blockIdx.x * 64 + l) * 8) = hv;
}

// ============================================================================
// MFMA MLP, single bf16 plane (32 KB LDS). X staged from bf16 (fast path) or
// fp32 (fallback). H relu'd back into the same LDS as bf16.
// ============================================================================
__global__ __launch_bounds__(256) void mlp_mfma_k(const float* __restrict__ emb,
        const bf16* __restrict__ embh,
        const float* nbrf, const bf16* __restrict__ nbrh,
        const bf16* __restrict__ w1h, const float* __restrict__ b1,
        const bf16* __restrict__ w2h, const float* __restrict__ b2,
        float* out, int N) {
    __shared__ char smem[BM * K1 * 2];  // 32 KB: [64 rows][256 cols] bf16
    const int t = threadIdx.x;
    const int n0 = blockIdx.x * BM;
    const int l = t & 63;
    const int w = t >> 6;

    // ---- stage X (swizzled: byte_in_row ^= (row&7)<<4) ----
    #pragma unroll
    for (int i = 0; i < 8; ++i) {
        int chunk = i * 256 + t;
        int row = chunk >> 5;
        int c0 = (chunk & 31) * 8;
        int n = n0 + row;
        bf16x8 hv;
        if (n < N) {
            if (embh != nullptr) {
                const bf16* sp = (c0 < DD) ? &embh[(size_t)n * DD + c0]
                                           : &nbrh[(size_t)n * DD + (c0 - DD)];
                hv = *reinterpret_cast<const bf16x8*>(sp);
            } else {
                const float* sp = (c0 < DD) ? &emb[(size_t)n * DD + c0]
                                            : &nbrf[(size_t)n * DD + (c0 - DD)];
                float4 a = *reinterpret_cast<const float4*>(sp);
                float4 b = *reinterpret_cast<const float4*>(sp + 4);
                hv[0]=(bf16)a.x; hv[1]=(bf16)a.y; hv[2]=(bf16)a.z; hv[3]=(bf16)a.w;
                hv[4]=(bf16)b.x; hv[5]=(bf16)b.y; hv[6]=(bf16)b.z; hv[7]=(bf16)b.w;
            }
        } else {
            #pragma unroll
            for (int j = 0; j < 8; ++j) hv[j] = (bf16)0.f;
        }
        int off = row * 512 + ((c0 * 2) ^ ((row & 7) << 4));
        *reinterpret_cast<bf16x8*>(smem + off) = hv;
    }
    __syncthreads();

    const int arow = l & 15;
    const int abyte = (l >> 4) * 16;

    // ---- GEMM1: wave w owns cols [w*64, w*64+64) of H ----
    f32x4 acc[4][4];
    #pragma unroll
    for (int ntl = 0; ntl < 4; ++ntl) {
        float bv = b1[w * 64 + ntl * 16 + (l & 15)];
        #pragma unroll
        for (int mt = 0; mt < 4; ++mt)
            acc[mt][ntl] = (f32x4){bv, bv, bv, bv};
    }
    for (int kt = 0; kt < 8; ++kt) {
        bf16x8 ah[4];
        #pragma unroll
        for (int mt = 0; mt < 4; ++mt) {
            int row = mt * 16 + arow;
            int off = row * 512 + ((kt * 64 + abyte) ^ ((row & 7) << 4));
            ah[mt] = *reinterpret_cast<const bf16x8*>(smem + off);
        }
        #pragma unroll
        for (int ntl = 0; ntl < 4; ++ntl) {
            int nt = w * 4 + ntl;
            size_t boff = ((size_t)(kt * 16 + nt) * 64 + l) * 8;
            bf16x8 bh = *reinterpret_cast<const bf16x8*>(w1h + boff);
            #pragma unroll
            for (int mt = 0; mt < 4; ++mt)
                acc[mt][ntl] = __builtin_amdgcn_mfma_f32_16x16x32_bf16(ah[mt], bh, acc[mt][ntl], 0, 0, 0);
        }
    }
    __syncthreads();  // all X reads done; LDS becomes H

    // ---- relu + write H bf16 (same swizzle) ----
    #pragma unroll
    for (int mt = 0; mt < 4; ++mt)
        #pragma unroll
        for (int ntl = 0; ntl < 4; ++ntl) {
            int col = w * 64 + ntl * 16 + (l & 15);
            #pragma unroll
            for (int r = 0; r < 4; ++r) {
                int row = mt * 16 + (l >> 4) * 4 + r;
                int off = row * 512 + ((col * 2) ^ ((row & 7) << 4));
                *reinterpret_cast<bf16*>(smem + off) = (bf16)fmaxf(acc[mt][ntl][r], 0.f);
            }
        }
    __syncthreads();

    // ---- GEMM2: wave w owns cols [w*32, w*32+32) of out ----
    f32x4 acc2[4][2];
    #pragma unroll
    for (int ntl = 0; ntl < 2; ++ntl) {
        float bv = b2[w * 32 + ntl * 16 + (l & 15)];
        #pragma unroll
        for (int mt = 0; mt < 4; ++mt)
            acc2[mt][ntl] = (f32x4){bv, bv, bv, bv};
    }
    for (int kt = 0; kt < 8; ++kt) {
        bf16x8 ah[4];
        #pragma unroll
        for (int mt = 0; mt < 4; ++mt) {
            int row = mt * 16 + arow;
            int off = row * 512 + ((kt * 64 + abyte) ^ ((row & 7) << 4));
            ah[mt] = *reinterpret_cast<const bf16x8*>(smem + off);
        }
        #pragma unroll
        for (int ntl = 0; ntl < 2; ++ntl) {
            int nt = w * 2 + ntl;
            size_t boff = ((size_t)(kt * 8 + nt) * 64 + l) * 8;
            bf16x8 bh = *reinterpret_cast<const bf16x8*>(w2h + boff);
            #pragma unroll
            for (int mt = 0; mt < 4; ++mt)
                acc2[mt][ntl] = __builtin_amdgcn_mfma_f32_16x16x32_bf16(ah[mt], bh, acc2[mt][ntl], 0, 0, 0);
        }
    }
    #pragma unroll
    for (int mt = 0; mt < 4; ++mt)
        #pragma unroll
        for (int ntl = 0; ntl < 2; ++ntl) {
            int col = w * 32 + ntl * 16 + (l & 15);
            #pragma unroll
            for (int r = 0; r < 4; ++r) {
                int row = mt * 16 + (l >> 4) * 4 + r;
                int n = n0 + row;
                if (n < N) out[(size_t)n * DD + col] = acc2[mt][ntl][r];
            }
        }
}

// ============================================================================
// fallback path (tiny ws): atomic scatter + fp32 VALU MLP
// ============================================================================
__global__ __launch_bounds__(256) void scatter_k(const float* __restrict__ emb,
        const int* __restrict__ src, const int* __restrict__ dst,
        float* nbr, float* __restrict__ cnt, int E) {
    int e = blockIdx.x * 8 + (threadIdx.x >> 5);
    if (e >= E) return;
    int lane = threadIdx.x & 31;
    int s = src[e];
    int d = dst[e];
    const float4 v = *reinterpret_cast<const float4*>(&emb[(size_t)s * DD + lane * 4]);
    float* o = &nbr[(size_t)d * DD + lane * 4];
    atomicAdd(o + 0, v.x);
    atomicAdd(o + 1, v.y);
    atomicAdd(o + 2, v.z);
    atomicAdd(o + 3, v.w);
    if (lane == 0) atomicAdd(&cnt[d], 1.0f);
}

__global__ __launch_bounds__(256) void mlp_k(const float* __restrict__ emb,
        const float* nbr, const float* cnt,
        const float* __restrict__ W1, const float* __restrict__ b1,
        const float* __restrict__ W2, const float* __restrict__ b2,
        float* out, int N) {
    __shared__ float smem[BM * K1];
    const int t = threadIdx.x;
    const int n0 = blockIdx.x * BM;
    #pragma unroll
    for (int it = 0; it < 16; ++it) {
        int idx = it * 256 + t;
        int r = idx >> 6;
        int c4 = idx & 63;
        int n = n0 + r;
        float4 v = make_float4(0.f, 0.f, 0.f, 0.f);
        if (n < N) {
            if (c4 < 32) {
                v = *reinterpret_cast<const float4*>(&emb[(size_t)n * DD + c4 * 4]);
            } else {
                float c = cnt[n];
                if (c > 0.f) {
                    v = *reinterpret_cast<const float4*>(&nbr[(size_t)n * DD + (c4 - 32) * 4]);
                    float inv = 1.f / c;
                    v.x *= inv; v.y *= inv; v.z *= inv; v.w *= inv;
                } else {
                    v = *reinterpret_cast<const float4*>(&emb[(size_t)n * DD + (c4 - 32) * 4]);
                }
            }
        }
        *reinterpret_cast<float4*>(&smem[idx * 4]) = v;
    }
    __syncthreads();
    const int tx = t & 31;
    const int ty = t >> 5;
    const int r0 = ty * 8;
    {
        const int c0 = tx * 8;
        float acc[8][8];
        const float4 bva = *reinterpret_cast<const float4*>(&b1[c0]);
        const float4 bvb = *reinterpret_cast<const float4*>(&b1[c0 + 4]);
        #pragma unroll
        for (int i = 0; i < 8; ++i) {
            acc[i][0] = bva.x; acc[i][1] = bva.y; acc[i][2] = bva.z; acc[i][3] = bva.w;
            acc[i][4] = bvb.x; acc[i][5] = bvb.y; acc[i][6] = bvb.z; acc[i][7] = bvb.w;
        }
        for (int k0 = 0; k0 < K1; k0 += 4) {
            float xs[8][4];
            #pragma unroll
            for (int i = 0; i < 8; ++i) {
                float4 xv = *reinterpret_cast<const float4*>(&smem[(r0 + i) * K1 + k0]);
                xs[i][0] = xv.x; xs[i][1] = xv.y; xs[i][2] = xv.z; xs[i][3] = xv.w;
            }
            #pragma unroll
            for (int kk = 0; kk < 4; ++kk) {
                const float4 wa = *reinterpret_cast<const float4*>(&W1[(size_t)(k0 + kk) * HH + c0]);
                const float4 wb = *reinterpret_cast<const float4*>(&W1[(size_t)(k0 + kk) * HH + c0 + 4]);
                #pragma unroll
                for (int i = 0; i < 8; ++i) {
                    float x = xs[i][kk];
                    acc[i][0] += x * wa.x; acc[i][1] += x * wa.y;
                    acc[i][2] += x * wa.z; acc[i][3] += x * wa.w;
                    acc[i][4] += x * wb.x; acc[i][5] += x * wb.y;
                    acc[i][6] += x * wb.z; acc[i][7] += x * wb.w;
                }
            }
        }
        __syncthreads();
        #pragma unroll
        for (int i = 0; i < 8; ++i) {
            float4 h0, h1;
            h0.x = fmaxf(acc[i][0], 0.f); h0.y = fmaxf(acc[i][1], 0.f);
            h0.z = fmaxf(acc[i][2], 0.f); h0.w = fmaxf(acc[i][3], 0.f);
            h1.x = fmaxf(acc[i][4], 0.f); h1.y = fmaxf(acc[i][5], 0.f);
            h1.z = fmaxf(acc[i][6], 0.f); h1.w = fmaxf(acc[i][7], 0.f);
            *reinterpret_cast<float4*>(&smem[(r0 + i) * HH + c0]) = h0;
            *reinterpret_cast<float4*>(&smem[(r0 + i) * HH + c0 + 4]) = h1;
        }
        __syncthreads();
    }
    {
        const int c0 = tx * 4;
        float acc[8][4];
        const float4 bv = *reinterpret_cast<const float4*>(&b2[c0]);
        #pragma unroll
        for (int i = 0; i < 8; ++i) {
            acc[i][0] = bv.x; acc[i][1] = bv.y; acc[i][2] = bv.z; acc[i][3] = bv.w;
        }
        for (int k0 = 0; k0 < HH; k0 += 4) {
            float hs[8][4];
            #pragma unroll
            for (int i = 0; i < 8; ++i) {
                float4 hv = *reinterpret_cast<const float4*>(&smem[(r0 + i) * HH + k0]);
                hs[i][0] = hv.x; hs[i][1] = hv.y; hs[i][2] = hv.z; hs[i][3] = hv.w;
            }
            #pragma unroll
            for (int kk = 0; kk < 4; ++kk) {
                const float4 w2 = *reinterpret_cast<const float4*>(&W2[(size_t)(k0 + kk) * DD + c0]);
                #pragma unroll
                for (int i = 0; i < 8; ++i) {
                    float h = hs[i][kk];
                    acc[i][0] += h * w2.x; acc[i][1] += h * w2.y;
                    acc[i][2] += h * w2.z; acc[i][3] += h * w2.w;
                }
            }
        }
        #pragma unroll
        for (int i = 0; i < 8; ++i) {
            int n = n0 + r0 + i;
            if (n < N) {
                float4 o;
                o.x = acc[i][0]; o.y = acc[i][1]; o.z = acc[i][2]; o.w = acc[i][3];
                *reinterpret_cast<float4*>(&out[(size_t)n * DD + c0]) = o;
            }
        }
    }
}

extern "C" void kernel_launch(void* const* d_in, const int* in_sizes, int n_in,
                              void* d_out, int out_size, void* d_ws, size_t ws_size,
                              hipStream_t stream) {
    const float* emb = (const float*)d_in[0];
    const int* esrc  = (const int*)d_in[1];
    const int* edst  = (const int*)d_in[2];
    const float* W1  = (const float*)d_in[3];
    const float* b1  = (const float*)d_in[4];
    const float* W2  = (const float*)d_in[5];
    const float* b2  = (const float*)d_in[6];
    float* out = (float*)d_out;

    const int N = in_sizes[0] / DD;
    const int E = in_sizes[1];
    const int nparts = (N + 1023) / 1024;

    // ws layout: cnt[N] offs[N] part[128] ssrc[E] | W packs | embh | nbrh
    int* cnt  = (int*)d_ws;
    int* offs = cnt + N;
    int* part = offs + N;
    int* ssrc = part + 128;
    char* wp = (char*)(ssrc + E);
    wp = (char*)(((uintptr_t)wp + 15) & ~(uintptr_t)15);
    bf16* w1h = (bf16*)wp;            // 65536 elems
    bf16* w2h = w1h + 65536;          // 32768 elems
    bf16* embh = w2h + 32768;         // N*DD elems
    bf16* nbrh = embh + (size_t)N * DD;  // N*DD elems
    const size_t need_base = (size_t)((char*)(w2h + 32768) - (char*)d_ws);
    const size_t need_full = (size_t)((char*)(nbrh + (size_t)N * DD) - (char*)d_ws);

    if (ws_size >= need_base && nparts <= 128) {
        const bool bf16_path = (ws_size >= need_full);
        hipMemsetAsync(cnt, 0, (size_t)N * sizeof(int), stream);
        hist_k<<<dim3(1024), dim3(256), 0, stream>>>(edst, cnt, E);
        scan1_k<<<dim3(nparts), dim3(256), 0, stream>>>(cnt, offs, part, N);
        scan2_k<<<dim3(1), dim3(128), 0, stream>>>(part, nparts);
        scan3_k<<<dim3(512), dim3(256), 0, stream>>>(offs, part, N);
        pack_k<<<dim3(128), dim3(64), 0, stream>>>(W1, HH, w1h);
        pack_k<<<dim3(64), dim3(64), 0, stream>>>(W2, DD, w2h);
        if (bf16_path)
            cvt_k<<<dim3(2048), dim3(256), 0, stream>>>(emb, embh, (size_t)N * DD / 8);
        const int nchunks = (E + CH - 1) / CH;
        bucket_k<<<dim3(nchunks * 8), dim3(256), 0, stream>>>(esrc, edst, offs, ssrc, E, N);
        if (bf16_path) {
            gather_bf16_k<<<dim3((N + 3) / 4), dim3(256), 0, stream>>>(embh, offs, ssrc, nbrh, N);
            mlp_mfma_k<<<dim3((N + BM - 1) / BM), dim3(256), 0, stream>>>(
                emb, embh, nullptr, nbrh, w1h, b1, w2h, b2, out, N);
        } else {
            gather_k<<<dim3((N + 3) / 4), dim3(256), 0, stream>>>(emb, offs, ssrc, out, N);
            mlp_mfma_k<<<dim3((N + BM - 1) / BM), dim3(256), 0, stream>>>(
                emb, nullptr, out, nullptr, w1h, b1, w2h, b2, out, N);
        }
    } else {
        float* fcnt = (float*)d_ws;
        hipMemsetAsync(out, 0, (size_t)N * DD * sizeof(float), stream);
        hipMemsetAsync(fcnt, 0, (size_t)N * sizeof(float), stream);
        scatter_k<<<dim3((E + 7) / 8), dim3(256), 0, stream>>>(emb, esrc, edst, out, fcnt, E);
        mlp_k<<<dim3((N + BM - 1) / BM), dim3(256), 0, stream>>>(
            emb, out, fcnt, W1, b1, W2, b2, out, N);
    }
}